// Round 11
// baseline (47786.542 us; speedup 1.0000x reference)
//
#include <hip/hip_runtime.h>
#include <math.h>

#define NWG 256
#define TPB 512
#define AGT __HIP_MEMORY_SCOPE_AGENT

// ---- sizes ----
static constexpr int Bb = 32, Dd = 512, Tt = 32, Vv = 32000;
static constexpr int BD = Bb * Dd;                       // 16384
static constexpr float SCALE_INV = 0.04419417382415922f; // 1/sqrt(512)

// ---- ws layout (float offsets). Sync region = first 32 KB. ----
// H0/H1/Hl use PAIRED layout: element (b,k) at [b>>1]*1024 + k*2 + (b&1).
static constexpr size_t OFF_H0 = 8192;
static constexpr size_t OFF_H1 = OFF_H0 + 2 * (size_t)BD;
static constexpr size_t OFF_P  = OFF_H1 + 2 * (size_t)BD;             // [32][32][2048]
static constexpr size_t OFF_HL = OFF_P + (size_t)Tt * Bb * 2048;      // [32] paired
static constexpr size_t OFF_HD = OFF_HL + (size_t)Tt * BD;
static constexpr size_t OFF_OF = OFF_HD + BD;                          // [32][32][512]
static constexpr size_t OFF_CV = OFF_OF + (size_t)Tt * BD;             // [32][256]
static constexpr size_t OFF_CI = OFF_CV + 32 * 256;
static constexpr size_t OFF_ET = OFF_CI + 32 * 256;                    // ETb [16000][512][2]

// ---- LDS (floats). LSTM WGs: 48 weight rows + 16KB stage. G WGs overlay low region. ----
static constexpr int L_W   = 0;       // 48 x 576 slant-packed = 27648
static constexpr int L_H   = 27648;   // 4096 floats (16KB): H quarter-stage / scratch overlay
static constexpr int LDS_FLOATS = 31744;
static constexpr size_t LDS_BYTES = (size_t)LDS_FLOATS * 4;   // 126976
// G-WG overlay (weights region unused by G WGs):
static constexpr int G_HB  = 0;       // 2048 hidT block [64k][32b] swizzled (also noET rb)
static constexpr int G_GV  = 2048;    // 256
static constexpr int G_GI  = 2304;    // 256
static constexpr int G_TOK = 2560;    // 32
// CDEF / Y scratch overlay (inside L_H stage region, free between AB phases):
static constexpr int S_SC  = L_H;          // 512
static constexpr int S_RB  = L_H + 512;    // 1024
static constexpr int S_IB  = L_H + 1536;   // 512
static constexpr int S_RED = L_H + 2048;   // 16

__device__ __forceinline__ float sigm(float x) { return 1.0f / (1.0f + expf(-x)); }

// ---- IC-coherent (sc1) access: relaxed agent-scope atomics ----
__device__ __forceinline__ float ldcv(const float* p) {
  unsigned u = __hip_atomic_load((const unsigned*)p, __ATOMIC_RELAXED, AGT);
  return __builtin_bit_cast(float, u);
}
__device__ __forceinline__ void stcv(float* p, float v) {
  __hip_atomic_store((unsigned*)p, __builtin_bit_cast(unsigned, v), __ATOMIC_RELAXED, AGT);
}
__device__ __forceinline__ float2 ldcv2(const float* p) {
  unsigned long long u = __hip_atomic_load((const unsigned long long*)p, __ATOMIC_RELAXED, AGT);
  return __builtin_bit_cast(float2, u);
}
__device__ __forceinline__ void stcv2(float* p, float2 v) {
  __hip_atomic_store((unsigned long long*)p, __builtin_bit_cast(unsigned long long, v),
                     __ATOMIC_RELAXED, AGT);
}
__device__ __forceinline__ int ldcvi(const int* p) {
  return (int)__hip_atomic_load((const unsigned*)p, __ATOMIC_RELAXED, AGT);
}
__device__ __forceinline__ void stcvi(int* p, int v) {
  __hip_atomic_store((unsigned*)p, (unsigned)v, __ATOMIC_RELAXED, AGT);
}

__device__ __forceinline__ float wredsum(float v) {
#pragma unroll
  for (int off = 32; off > 0; off >>= 1) v += __shfl_xor(v, off, 64);
  return v;
}

// DPP rotate-reduce within each 16-lane row (pure VALU).
__device__ __forceinline__ float rowReduce16(float x) {
  int t;
  t = __builtin_amdgcn_update_dpp(0, __builtin_bit_cast(int, x), 0x121, 0xF, 0xF, false);
  x += __builtin_bit_cast(float, t);
  t = __builtin_amdgcn_update_dpp(0, __builtin_bit_cast(int, x), 0x122, 0xF, 0xF, false);
  x += __builtin_bit_cast(float, t);
  t = __builtin_amdgcn_update_dpp(0, __builtin_bit_cast(int, x), 0x124, 0xF, 0xF, false);
  x += __builtin_bit_cast(float, t);
  t = __builtin_amdgcn_update_dpp(0, __builtin_bit_cast(int, x), 0x128, 0xF, 0xF, false);
  x += __builtin_bit_cast(float, t);
  return x;
}

// ---- contention-free 2-level slot barrier (r8-proven, full 256 WGs) ----
__device__ __forceinline__ void gbar(unsigned* sb, unsigned& lg) {
  const unsigned tgt = lg + 1u;
  asm volatile("s_waitcnt vmcnt(0)" ::: "memory");
  __syncthreads();
  const int wg = (int)blockIdx.x;
  if (threadIdx.x < 64) {
    const int lane = (int)threadIdx.x;
    if (lane == 0)
      __hip_atomic_store(&sb[wg * 16], tgt, __ATOMIC_RELAXED, AGT);
    const int g = wg >> 5;
    if ((wg & 31) == 0) {                       // group leader
      if (lane < 32) {
        const unsigned* slot = &sb[(g * 32 + lane) * 16];
        while (__hip_atomic_load(slot, __ATOMIC_RELAXED, AGT) < tgt)
          __builtin_amdgcn_s_sleep(1);
      }
      if (lane == 0)
        __hip_atomic_store(&sb[4096 + g * 16], tgt, __ATOMIC_RELAXED, AGT);
    }
    if (lane < 8) {
      const unsigned* f = &sb[4096 + lane * 16];
      while (__hip_atomic_load(f, __ATOMIC_RELAXED, AGT) < tgt)
        __builtin_amdgcn_s_sleep(1);
    }
  }
  lg = tgt;
  __syncthreads();
}

__device__ __forceinline__ float blockMax(float v, float* red, int tid) {
#pragma unroll
  for (int off = 32; off > 0; off >>= 1) v = fmaxf(v, __shfl_xor(v, off, 64));
  if ((tid & 63) == 0) red[tid >> 6] = v;
  __syncthreads();
  float m = red[0];
#pragma unroll
  for (int i = 1; i < 8; ++i) m = fmaxf(m, red[i]);
  __syncthreads();
  return m;
}

__device__ __forceinline__ float blockSum(float v, float* red, int tid) {
  v = wredsum(v);
  if ((tid & 63) == 0) red[tid >> 6] = v;
  __syncthreads();
  float s = 0.f;
#pragma unroll
  for (int i = 0; i < 8; ++i) s += red[i];
  __syncthreads();
  return s;
}

// ---- stage 48 weight rows (4 cols/WG), slant-packed: rr = m*16 + q*4 + dl ----
__device__ void stageW4(int wg, int tid, const float* __restrict__ Wih,
                        const float* __restrict__ Whh, float* __restrict__ SMW) {
  for (int e = tid; e < 48 * 512; e += TPB) {
    const int k = e & 511, rr = e >> 9;
    const int m = rr >> 4, q = (rr >> 2) & 3, dl = rr & 3;
    const int j = q * 512 + wg * 4 + dl;
    const float* srcp = (m == 0) ? (Whh + (size_t)j * 512)
                     : (m == 1) ? (Wih + (size_t)2048 * 512 + (size_t)j * 512)
                                : (Whh + (size_t)2048 * 512 + (size_t)j * 512);
    SMW[rr * 576 + (k >> 5) * 36 + (k & 31)] = srcp[k];
  }
  __syncthreads();
}

// ---- WG-private build of ETb[v/2][k][2] (panel [wg*128, +128)); sc1 stores ----
__device__ void buildETb(int wg, int tid, const float* __restrict__ Etrg,
                         float* __restrict__ ETb, float* __restrict__ SM) {
  if (wg < 250) {
    for (int tile = 0; tile < 8; ++tile) {
      const int tv = tile >> 2, tk = tile & 3;
      __syncthreads();
      for (int e = tid; e < 64 * 128; e += TPB) {
        const int vl = e >> 7, kl = e & 127;
        SM[vl * 129 + kl] = Etrg[(size_t)(wg * 128 + tv * 64 + vl) * 512 + tk * 128 + kl];
      }
      __syncthreads();
      for (int e = tid; e < 32 * 128; e += TPB) {
        const int vp = e >> 7, kl = e & 127;
        const int v = wg * 128 + tv * 64 + vp * 2;
        const int k = tk * 128 + kl;
        float2 val = make_float2(SM[(vp * 2) * 129 + kl], SM[(vp * 2 + 1) * 129 + kl]);
        stcv2(ETb + ((size_t)(v >> 1) * 512 + k) * 2, val);
      }
    }
    __syncthreads();
  }
}

// ---- phaseAB4 helpers: quarter-staged H (16 KB), vmcnt(0)-only waits ----
__device__ __forceinline__ void ld2q(const float* base, int tid, float4 s[2]) {
  const float* p0 = base + tid * 4;
  const float* p1 = base + 2048 + tid * 4;
  asm volatile("global_load_dwordx4 %0, %1, off sc1" : "=v"(s[0]) : "v"(p0));
  asm volatile("global_load_dwordx4 %0, %1, off sc1" : "=v"(s[1]) : "v"(p1));
}
__device__ __forceinline__ void stage2(char* LHc, int tid, const float4 s[2]) {
  int byA = tid * 16;         byA ^= ((byA >> 8) & 7) << 4;
  int byB = (512 + tid) * 16; byB ^= ((byB >> 8) & 7) << 4;
  *(float4*)(LHc + byA) = s[0];
  *(float4*)(LHc + byB) = s[1];
}
__device__ __forceinline__ void readHq4(const char* LHc, int b2l, int kc, float4 hq[16]) {
#pragma unroll
  for (int i = 0; i < 16; ++i) {
    int byte = b2l * 4096 + kc * 256 + i * 16;
    byte ^= ((byte >> 8) & 7) << 4;
    hq[i] = *(const float4*)(LHc + byte);
  }
}
// dot of slant-packed W row rr with paired H fragments -> float2 (b even, b odd)
__device__ __forceinline__ void dotMQ(const float* __restrict__ SMW, int rr, int kc,
                                      const float4* __restrict__ hq, float2& acc) {
  const float4* wr = (const float4*)(SMW + rr * 576 + kc * 36);
#pragma unroll
  for (int i2 = 0; i2 < 8; ++i2) {
    const float4 wv = wr[i2];
    const float4 hA = hq[i2 * 2], hB = hq[i2 * 2 + 1];
    acc.x = fmaf(wv.x, hA.x, acc.x); acc.y = fmaf(wv.x, hA.y, acc.y);
    acc.x = fmaf(wv.y, hA.z, acc.x); acc.y = fmaf(wv.y, hA.w, acc.y);
    acc.x = fmaf(wv.z, hB.x, acc.x); acc.y = fmaf(wv.z, hB.y, acc.y);
    acc.x = fmaf(wv.w, hB.z, acc.x); acc.y = fmaf(wv.w, hB.w, acc.y);
  }
}

// ---- merged LSTM phase, 4 cols/WG (WGs 0..127). tid = b2*32 + dh*16 + kc. ----
__device__ __forceinline__ void phaseAB4(
    int wg, int tid, bool doA, bool doB,
    const float* __restrict__ H0r, float* __restrict__ H0w,
    const float* __restrict__ H1r, float* __restrict__ H1w,
    float* __restrict__ HlP, const float* __restrict__ Pp,
    const float bs1v[2][4], const float* __restrict__ SMW, float* __restrict__ LH,
    float c0[2][2], float c1[2][2])
{
  const int b2 = tid >> 5, dh = (tid >> 4) & 1, kc = tid & 15;
  const int q4 = b2 >> 2, b2l = b2 & 3;
  char* LHc = (char*)LH;
  float4 s[2], hq[16];

  // ---- H0: 4 quarter-rounds (16 KB each), vmcnt(0)-only ----
  ld2q(H0r, tid, s);
#pragma unroll
  for (int qq = 0; qq < 4; ++qq) {
    asm volatile("s_waitcnt vmcnt(0)" ::: "memory");
    __builtin_amdgcn_sched_barrier(0);
    stage2(LHc, tid, s);
    if (qq < 3) ld2q(H0r + (qq + 1) * 4096, tid, s);
    else if (doB) ld2q(H1r, tid, s);         // first H1 quarter flies under dots
    __syncthreads();
    if (q4 == qq) readHq4(LHc, b2l, kc, hq);
    __syncthreads();
  }

  float2 a2[2][12];
#pragma unroll
  for (int dlx = 0; dlx < 2; ++dlx)
#pragma unroll
    for (int j = 0; j < 12; ++j) a2[dlx][j] = make_float2(0.f, 0.f);

  if (doA) {
#pragma unroll
    for (int dlx = 0; dlx < 2; ++dlx)
#pragma unroll
      for (int q = 0; q < 4; ++q)
        dotMQ(SMW, q * 4 + dh * 2 + dlx, kc, hq, a2[dlx][q]);          // Whh0.H0
  }
  if (doB) {
#pragma unroll
    for (int dlx = 0; dlx < 2; ++dlx)
#pragma unroll
      for (int q = 0; q < 4; ++q)
        dotMQ(SMW, 16 + q * 4 + dh * 2 + dlx, kc, hq, a2[dlx][4 + q]); // Wih1.H0
    // ---- H1: 4 quarter-rounds ----
#pragma unroll
    for (int qq = 0; qq < 4; ++qq) {
      asm volatile("s_waitcnt vmcnt(0)" ::: "memory");
      __builtin_amdgcn_sched_barrier(0);
      stage2(LHc, tid, s);
      if (qq < 3) ld2q(H1r + (qq + 1) * 4096, tid, s);
      __syncthreads();
      if (q4 == qq) readHq4(LHc, b2l, kc, hq);
      __syncthreads();
    }
#pragma unroll
    for (int dlx = 0; dlx < 2; ++dlx)
#pragma unroll
      for (int q = 0; q < 4; ++q)
        dotMQ(SMW, 32 + q * 4 + dh * 2 + dlx, kc, hq, a2[dlx][8 + q]); // Whh1.H1
  }

#pragma unroll
  for (int dlx = 0; dlx < 2; ++dlx)
#pragma unroll
    for (int j = 0; j < 12; ++j) {
      if (j < 4 ? !doA : !doB) continue;
      a2[dlx][j].x = rowReduce16(a2[dlx][j].x);
      a2[dlx][j].y = rowReduce16(a2[dlx][j].y);
    }

  if (kc == 0) {                      // 32 lanes own (b2, dh); 2 cols each
#pragma unroll
    for (int dlx = 0; dlx < 2; ++dlx) {
      const int d = (wg << 2) | (dh << 1) | dlx;
      if (doA) {
#pragma unroll
        for (int p = 0; p < 2; ++p) {
          const int b = b2 * 2 + p;
          const float* pb = Pp + b * 2048 + d;
          const float gi = (p ? a2[dlx][0].y : a2[dlx][0].x) + pb[0];
          const float gf = (p ? a2[dlx][1].y : a2[dlx][1].x) + pb[512];
          const float gg = (p ? a2[dlx][2].y : a2[dlx][2].x) + pb[1024];
          const float go = (p ? a2[dlx][3].y : a2[dlx][3].x) + pb[1536];
          c0[dlx][p] = sigm(gf) * c0[dlx][p] + sigm(gi) * tanhf(gg);
          stcv(H0w + b2 * 1024 + d * 2 + p, sigm(go) * tanhf(c0[dlx][p]));
        }
      }
      if (doB) {
#pragma unroll
        for (int p = 0; p < 2; ++p) {
          const float gi = (p ? a2[dlx][4].y : a2[dlx][4].x) + (p ? a2[dlx][8].y  : a2[dlx][8].x)  + bs1v[dlx][0];
          const float gf = (p ? a2[dlx][5].y : a2[dlx][5].x) + (p ? a2[dlx][9].y  : a2[dlx][9].x)  + bs1v[dlx][1];
          const float gg = (p ? a2[dlx][6].y : a2[dlx][6].x) + (p ? a2[dlx][10].y : a2[dlx][10].x) + bs1v[dlx][2];
          const float go = (p ? a2[dlx][7].y : a2[dlx][7].x) + (p ? a2[dlx][11].y : a2[dlx][11].x) + bs1v[dlx][3];
          c1[dlx][p] = sigm(gf) * c1[dlx][p] + sigm(gi) * tanhf(gg);
          const float hn = sigm(go) * tanhf(c1[dlx][p]);
          stcv(H1w + b2 * 1024 + d * 2 + p, hn);
          if (HlP) stcv(HlP + b2 * 1024 + d * 2 + p, hn);
        }
      }
    }
  }
}

// ---- fused fc + attention + context + h2o for one batch row (WGs 0..31) ----
__device__ void phaseCDEF(int b, int tid, const float* __restrict__ H1c,
                          const float* __restrict__ Wfc, const float* __restrict__ bfc,
                          const int* __restrict__ src, const float* __restrict__ Esrc,
                          const float* __restrict__ Wh2o, const float* __restrict__ bh2o,
                          float* __restrict__ hD, float* sc, float* rb, int* ib, float* red)
{
  rb[tid] = ldcv(H1c + (b >> 1) * 1024 + tid * 2 + (b & 1));  // paired layout
  ib[tid] = src[b * 512 + tid];
  __syncthreads();
  const int w = tid >> 6, lane = tid & 63;
  for (int d = w; d < 512; d += 8) {            // fc_out
    const float* wr = Wfc + (size_t)d * 512;
    float p = 0.f;
#pragma unroll
    for (int i = 0; i < 8; ++i) p = fmaf(rb[lane * 8 + i], wr[lane * 8 + i], p);
    p = wredsum(p);
    if (lane == 0) rb[512 + d] = p + bfc[d];
  }
  __syncthreads();
  for (int s = w; s < 512; s += 8) {            // scores
    const float* er = Esrc + (size_t)ib[s] * 512;
    float p = 0.f;
#pragma unroll
    for (int i = 0; i < 8; ++i) p = fmaf(rb[512 + lane * 8 + i], er[lane * 8 + i], p);
    p = wredsum(p);
    if (lane == 0) sc[s] = p * SCALE_INV;
  }
  __syncthreads();
  const float mx = blockMax(sc[tid], red, tid);
  const float e = expf(sc[tid] - mx);
  sc[tid] = e;
  const float sum = blockSum(e, red, tid);
  const float inv = 1.0f / sum;
  float acc = 0.f;
#pragma unroll 4
  for (int s = 0; s < 512; ++s) acc = fmaf(sc[s], Esrc[(size_t)ib[s] * 512 + tid], acc);
  rb[tid] = acc * inv;                          // ctx
  __syncthreads();
  for (int d = w; d < 512; d += 8) {            // h2o + relu
    const float* wr = Wh2o + (size_t)d * 1024;
    float p = 0.f;
#pragma unroll
    for (int i = 0; i < 8; ++i) p = fmaf(rb[512 + lane * 8 + i], wr[lane * 8 + i], p);
#pragma unroll
    for (int i = 0; i < 8; ++i) p = fmaf(rb[lane * 8 + i], wr[512 + lane * 8 + i], p);
    p = wredsum(p);
    if (lane == 0) stcv(hD + (size_t)b * 512 + d, fmaxf(p + bh2o[d], 0.f));
  }
  __syncthreads();
}

// ---- logits panel chunk: 256 v per G WG, k-half per chunk, all 32 b ----
__device__ void phaseG_panelC(int wgG, int tid, int chunk, float (*acc)[4],
                              const float* __restrict__ hD, const float* __restrict__ ETb,
                              const float* __restrict__ bout, float* __restrict__ candV,
                              int* __restrict__ candI, float* __restrict__ hblk,
                              float* __restrict__ gv, int* __restrict__ gi)
{
  if (wgG >= 125) return;
  if (chunk == 0) {
#pragma unroll
    for (int a = 0; a < 4; ++a)
#pragma unroll
      for (int b = 0; b < 4; ++b) acc[a][b] = 0.f;
  }
  const int vp = tid >> 3, bh = tid & 7;
  const int v0 = wgG * 256 + vp * 4;
  const float* epA = ETb + (size_t)(v0 >> 1) * 1024 + chunk * 512;
  const float* epB = epA + 1024;
  const int fk = tid & 63, fb0 = tid >> 6;
  char* hb = (char*)hblk;

  for (int blk = 0; blk < 4; ++blk) {
    const int kb = chunk * 256 + blk * 64;
    __syncthreads();
#pragma unroll
    for (int i = 0; i < 4; ++i) {
      const int b = fb0 + i * 8;
      const float hv = ldcv(hD + (size_t)b * 512 + kb + fk);
      const int byte = fk * 128 + (((b >> 2) * 16) ^ ((fk & 7) << 4)) + ((b & 3) << 2);
      *(float*)(hb + byte) = hv;
    }
    __syncthreads();
#pragma unroll 8
    for (int kk = 0; kk < 64; kk += 2) {
      const float4 eA = *(const float4*)epA; epA += 4;
      const float4 eB = *(const float4*)epB; epB += 4;
      const float4 h0 = *(const float4*)(hb + kk * 128 + ((bh * 16) ^ ((kk & 7) << 4)));
      const float4 h1 = *(const float4*)(hb + (kk + 1) * 128 + ((bh * 16) ^ (((kk + 1) & 7) << 4)));
#pragma unroll
      for (int bj = 0; bj < 4; ++bj) {
        const float h0v = (bj == 0) ? h0.x : (bj == 1) ? h0.y : (bj == 2) ? h0.z : h0.w;
        const float h1v = (bj == 0) ? h1.x : (bj == 1) ? h1.y : (bj == 2) ? h1.z : h1.w;
        acc[0][bj] = fmaf(eA.x, h0v, acc[0][bj]);
        acc[0][bj] = fmaf(eA.z, h1v, acc[0][bj]);
        acc[1][bj] = fmaf(eA.y, h0v, acc[1][bj]);
        acc[1][bj] = fmaf(eA.w, h1v, acc[1][bj]);
        acc[2][bj] = fmaf(eB.x, h0v, acc[2][bj]);
        acc[2][bj] = fmaf(eB.z, h1v, acc[2][bj]);
        acc[3][bj] = fmaf(eB.y, h0v, acc[3][bj]);
        acc[3][bj] = fmaf(eB.w, h1v, acc[3][bj]);
      }
    }
  }
  if (chunk == 1) {
    const float bo[4] = {bout[v0], bout[v0 + 1], bout[v0 + 2], bout[v0 + 3]};
    const int w = tid >> 6;
#pragma unroll
    for (int bj = 0; bj < 4; ++bj) {
      float bv = acc[0][bj] + bo[0]; int bi = v0;
#pragma unroll
      for (int vj = 1; vj < 4; ++vj) {
        const float vv = acc[vj][bj] + bo[vj];
        if (vv > bv) { bv = vv; bi = v0 + vj; }
      }
#pragma unroll
      for (int off = 8; off < 64; off <<= 1) {
        const float ov = __shfl_xor(bv, off, 64); const int oi = __shfl_xor(bi, off, 64);
        if (ov > bv || (ov == bv && oi < bi)) { bv = ov; bi = oi; }
      }
      if ((tid & 63) < 8) {
        gv[(bh * 4 + bj) * 8 + w] = bv;
        gi[(bh * 4 + bj) * 8 + w] = bi;
      }
    }
    __syncthreads();
    if (tid < 32) {
      float bv = -INFINITY; int bi = 0;
      for (int w2 = 0; w2 < 8; ++w2) {
        const float vv = gv[tid * 8 + w2]; const int ii = gi[tid * 8 + w2];
        if (vv > bv || (vv == bv && ii < bi)) { bv = vv; bi = ii; }
      }
      stcv(candV + (size_t)tid * 256 + wgG, bv);
      stcvi(candI + tid * 256 + wgG, bi);
    }
    __syncthreads();
  }
}

// ---- fallback logits (row-major Etrg): 250 v per G WG, 32 b sequential ----
__device__ void phaseG_noET2(int wgG, int tid, const float* __restrict__ hD,
                             const float* __restrict__ Etrg, const float* __restrict__ bout,
                             float* __restrict__ candV, int* __restrict__ candI,
                             float* rb, float* gv, int* gi)
{
  const int w = tid >> 6, lane = tid & 63;
  for (int b = 0; b < 32; ++b) {
    __syncthreads();
    rb[tid & 511] = ldcv(hD + (size_t)b * 512 + (tid & 511));
    __syncthreads();
    float bv = -INFINITY; int bi = 0x7fffffff;
    for (int v = wgG * 250 + w; v < wgG * 250 + 250; v += 8) {
      const float* er = Etrg + (size_t)v * 512;
      float p = 0.f;
#pragma unroll
      for (int i = 0; i < 8; ++i) p = fmaf(rb[lane * 8 + i], er[lane * 8 + i], p);
      p = wredsum(p);
      p += bout[v];
      if (p > bv || (p == bv && v < bi)) { bv = p; bi = v; }
    }
    if (lane == 0) { gv[w] = bv; gi[w] = bi; }
    __syncthreads();
    if (tid == 0) {
      float fv = -INFINITY; int fi = 0x7fffffff;
      for (int w2 = 0; w2 < 8; ++w2)
        if (gv[w2] > fv || (gv[w2] == fv && gi[w2] < fi)) { fv = gv[w2]; fi = gi[w2]; }
      stcv(candV + (size_t)b * 256 + wgG, fv);
      stcvi(candI + b * 256 + wgG, fi);
    }
  }
  __syncthreads();
}

// ---- token argmax finalize + this G WG's 16 rows of P[t+1] ----
__device__ void phaseHP_G(int wgG, int tid, int t, int nslot,
                          const float* __restrict__ candV, const int* __restrict__ candI,
                          const float* __restrict__ Etrg, const float* __restrict__ Wih,
                          const float* __restrict__ bih, const float* __restrict__ bhh,
                          float* __restrict__ P, float* __restrict__ out, int* tokL)
{
  {
    const int b = tid >> 4, sl = tid & 15;
    float bv = -INFINITY; int bi = 0x7fffffff;
    for (int s = sl; s < nslot; s += 16) {
      const float vv = ldcv(candV + (size_t)b * 256 + s);
      const int ii = ldcvi(candI + b * 256 + s);
      if (vv > bv || (vv == bv && ii < bi)) { bv = vv; bi = ii; }
    }
#pragma unroll
    for (int off = 1; off < 16; off <<= 1) {
      const float ov = __shfl_xor(bv, off, 64); const int oi = __shfl_xor(bi, off, 64);
      if (ov > bv || (ov == bv && oi < bi)) { bv = ov; bi = oi; }
    }
    if (sl == 0) {
      tokL[b] = bi;
      if (wgG == 0) stcv(out + b * 32 + t, (float)bi);   // tokens[:,1:][b][t]
    }
  }
  __syncthreads();
  if (t < 31) {
    const int w = tid >> 6, lane = tid & 63;
    for (int jj = w; jj < 16; jj += 8) {
      const int j = wgG * 16 + jj;
      const float* wr = Wih + (size_t)j * 512;
      const float bsum = bih[j] + bhh[j];
      for (int b = 0; b < 32; ++b) {
        const float* er = Etrg + (size_t)tokL[b] * 512;
        float p = 0.f;
#pragma unroll
        for (int i = 0; i < 8; ++i) p = fmaf(er[lane * 8 + i], wr[lane * 8 + i], p);
        p = wredsum(p);
        if (lane == 0) stcv(P + ((size_t)(t + 1) * 32 + b) * 2048 + j, p + bsum);
      }
    }
  }
  __syncthreads();
}

// ---- outfc[p][b][:] = Hlast[p][b] @ Wfc^T + bfc (paired Hl; 1 unit/WG) ----
__device__ void phaseX(int wg, int tid, const float* __restrict__ Hl, const float* __restrict__ Wfc,
                       const float* __restrict__ bfc, float* __restrict__ oF)
{
  const int p = wg >> 3, bq = wg & 7;
  const int w = tid >> 6, lane = tid & 63;
  for (int u = w; u < 1024; u += 8) {
    const int b2 = bq * 2 + (u >> 9), d = u & 511;
    const float* hr = Hl + (size_t)p * BD + b2 * 1024;
    const float* wr = Wfc + (size_t)d * 512;
    float ax = 0.f, ay = 0.f;
#pragma unroll
    for (int i = 0; i < 8; ++i) {
      const float2 hv = ldcv2(hr + (lane * 8 + i) * 2);
      const float wv = wr[lane * 8 + i];
      ax = fmaf(hv.x, wv, ax);
      ay = fmaf(hv.y, wv, ay);
    }
    ax = wredsum(ax); ay = wredsum(ay);
    if (lane == 0) {
      stcv(oF + ((size_t)p * 32 + b2 * 2    ) * 512 + d, ax + bfc[d]);
      stcv(oF + ((size_t)p * 32 + b2 * 2 + 1) * 512 + d, ay + bfc[d]);
    }
  }
}

// ---- final attn rows: 4 per WG ----
__device__ void phaseY(int wg, int tid, const float* __restrict__ oF, const int* __restrict__ src,
                       const float* __restrict__ Esrc, float* __restrict__ out,
                       float* sc, float* rb, int* ib, float* red)
{
  for (int r = 0; r < 4; ++r) {
    const int id = wg * 4 + r;
    const int b = id >> 5, p = id & 31;
    __syncthreads();
    rb[tid] = ldcv(oF + ((size_t)p * 32 + b) * 512 + tid);
    ib[tid] = src[b * 512 + tid];
    __syncthreads();
    const int w = tid >> 6, lane = tid & 63;
    for (int s = w; s < 512; s += 8) {
      const float* er = Esrc + (size_t)ib[s] * 512;
      float acc = 0.f;
#pragma unroll
      for (int i = 0; i < 8; ++i) acc = fmaf(rb[lane * 8 + i], er[lane * 8 + i], acc);
      acc = wredsum(acc);
      if (lane == 0) sc[s] = acc * SCALE_INV;
    }
    __syncthreads();
    const float mx = blockMax(sc[tid], red, tid);
    const float e = expf(sc[tid] - mx);
    const float sum = blockSum(e, red, tid);
    out[1024 + ((size_t)b * 32 + p) * 512 + tid] = e / sum;
  }
}

extern "C" __global__ void __launch_bounds__(TPB)
s2s_mega(const int* __restrict__ src, const float* __restrict__ Esrc, const float* __restrict__ Etrg,
         const float* __restrict__ Wih, const float* __restrict__ Whh,
         const float* __restrict__ bih, const float* __restrict__ bhh,
         const float* __restrict__ Wfc, const float* __restrict__ bfc,
         const float* __restrict__ Wh2o, const float* __restrict__ bh2o,
         const float* __restrict__ bout, float* __restrict__ out,
         float* __restrict__ ws, const float* __restrict__ ET, float* __restrict__ ETw)
{
  extern __shared__ float SM[];
  float* SMW = SM + L_W;
  float* LH  = SM + L_H;
  // overlays
  float* hblk = SM + G_HB;
  float* gv  = SM + G_GV;
  int*   gi  = (int*)(SM + G_GI);
  int*   tokG = (int*)(SM + G_TOK);
  float* scY = SM + S_SC;
  float* rbY = SM + S_RB;
  int*   ibY = (int*)(SM + S_IB);
  float* redY = SM + S_RED;

  unsigned* sb = (unsigned*)ws;
  float* H0 = ws + OFF_H0;
  float* H1 = ws + OFF_H1;
  float* P  = ws + OFF_P;
  float* Hl = ws + OFF_HL;
  float* hD = ws + OFF_HD;
  float* oF = ws + OFF_OF;
  float* cV = ws + OFF_CV;
  int*   cI = (int*)(ws + OFF_CI);

  const int wg = blockIdx.x, tid = threadIdx.x;
  const bool useET = (ET != nullptr);
  unsigned lg = 0u;
  float c0[2][2] = {{0.f, 0.f}, {0.f, 0.f}};
  float c1[2][2] = {{0.f, 0.f}, {0.f, 0.f}};
  float accG[4][4];
  float bs1v[2][4] = {{0.f,0.f,0.f,0.f},{0.f,0.f,0.f,0.f}};

  if (wg < 128) {       // layer-1 bias sums for this WG's 4 columns
    const int dh = (tid >> 4) & 1;
#pragma unroll
    for (int dlx = 0; dlx < 2; ++dlx) {
      const int d = (wg << 2) | (dh << 1) | dlx;
#pragma unroll
      for (int q = 0; q < 4; ++q)
        bs1v[dlx][q] = bih[2048 + q * 512 + d] + bhh[2048 + q * 512 + d];
    }
  }

  // ---- setup: zero carried H state ----
  {
    const int gid = wg * TPB + tid;
    if (gid < BD) stcv(H0 + gid, 0.f);
    else if (gid < 2 * BD) stcv(H1 + gid - BD, 0.f);
  }
  // ---- P[0] = emb([SOS]) @ Wih0^T + biases (all 256 WGs, 8 rows each) ----
  {
    const int w = tid >> 6, lane = tid & 63;
    const int q = w >> 1, dl = w & 1;
    const int j = q * 512 + wg * 2 + dl;
    const float* er = Etrg + 512;               // token 1 ([SOS])
    const float* wr = Wih + (size_t)j * 512;
    float p = 0.f;
#pragma unroll
    for (int i = 0; i < 8; ++i) p = fmaf(er[lane * 8 + i], wr[lane * 8 + i], p);
    p = wredsum(p);
    p += bih[j] + bhh[j];
    if (lane < 32) stcv(P + (size_t)lane * 2048 + j, p);
  }
  if (ETw) buildETb(wg, tid, Etrg, ETw, SM);
  if (wg < 128) stageW4(wg, tid, Wih, Whh, SMW);
  gbar(sb, lg);

  int cur0 = 0, cur1 = 0;
  for (int t = 0; t < 32; ++t) {
    for (int k = 0; k <= t + 1; ++k) {
      const bool doA = (k <= t), doB = (k >= 1);
      if (wg < 128) {
        float* HlP = (t == 31 && doB) ? (Hl + (size_t)(k - 1) * BD) : nullptr;
        const int kp = (k < 32) ? k : 31;
        phaseAB4(wg, tid, doA, doB,
                 H0 + (size_t)cur0 * BD, H0 + (size_t)(cur0 ^ 1) * BD,
                 H1 + (size_t)cur1 * BD, H1 + (size_t)(cur1 ^ 1) * BD,
                 HlP, P + (size_t)kp * Bb * 2048, bs1v, SMW, LH, c0, c1);
      } else {
        const int wgG = wg - 128;
        if (useET) {
          if (t >= 2 && k == 0) {
            phaseG_panelC(wgG, tid, 0, accG, hD, ET, bout, cV, cI, hblk, gv, gi);
            if (t == 2) phaseG_panelC(wgG, tid, 1, accG, hD, ET, bout, cV, cI, hblk, gv, gi);
          }
          if (t >= 3 && k == 1)
            phaseG_panelC(wgG, tid, 1, accG, hD, ET, bout, cV, cI, hblk, gv, gi);
          if (t == 2 && k == 1)
            phaseHP_G(wgG, tid, 1, 125, cV, cI, Etrg, Wih, bih, bhh, P, out, tokG);
          if (t >= 3 && k == 2)
            phaseHP_G(wgG, tid, t - 1, 125, cV, cI, Etrg, Wih, bih, bhh, P, out, tokG);
        } else {
          if (t >= 2 && k == 0)
            phaseG_noET2(wgG, tid, hD, Etrg, bout, cV, cI, hblk, gv, gi);
          if (t == 2 && k == 1)
            phaseHP_G(wgG, tid, 1, 128, cV, cI, Etrg, Wih, bih, bhh, P, out, tokG);
          if (t >= 3 && k == 2)
            phaseHP_G(wgG, tid, t - 1, 128, cV, cI, Etrg, Wih, bih, bhh, P, out, tokG);
        }
      }
      gbar(sb, lg);
      if (doA) cur0 ^= 1;
      if (doB) cur1 ^= 1;
    }
    if (wg < 32) phaseCDEF(wg, tid, H1 + (size_t)cur1 * BD, Wfc, bfc, src, Esrc,
                           Wh2o, bh2o, hD, scY, rbY, ibY, redY);
    gbar(sb, lg);
    if (t == 0) {       // bootstrap: G(0) + HP(0) standalone
      if (wg >= 128) {
        const int wgG = wg - 128;
        if (useET) {
          phaseG_panelC(wgG, tid, 0, accG, hD, ET, bout, cV, cI, hblk, gv, gi);
          phaseG_panelC(wgG, tid, 1, accG, hD, ET, bout, cV, cI, hblk, gv, gi);
        } else {
          phaseG_noET2(wgG, tid, hD, Etrg, bout, cV, cI, hblk, gv, gi);
        }
      }
      gbar(sb, lg);
      if (wg >= 128)
        phaseHP_G(wg - 128, tid, 0, useET ? 125 : 128, cV, cI, Etrg, Wih, bih, bhh, P, out, tokG);
      gbar(sb, lg);
    }
  }
  // ---- tail: X + G(31); then HP(31) token finalize + Y ----
  phaseX(wg, tid, Hl, Wfc, bfc, oF);
  if (wg >= 128) {
    const int wgG = wg - 128;
    if (useET) {
      phaseG_panelC(wgG, tid, 0, accG, hD, ET, bout, cV, cI, hblk, gv, gi);
      phaseG_panelC(wgG, tid, 1, accG, hD, ET, bout, cV, cI, hblk, gv, gi);
    } else {
      phaseG_noET2(wgG, tid, hD, Etrg, bout, cV, cI, hblk, gv, gi);
    }
  }
  gbar(sb, lg);
  if (wg >= 128)
    phaseHP_G(wg - 128, tid, 31, useET ? 125 : 128, cV, cI, Etrg, Wih, bih, bhh, P, out, tokG);
  phaseY(wg, tid, oF, src, Esrc, out, scY, rbY, ibY, redY);
}

extern "C" void kernel_launch(void* const* d_in, const int* in_sizes, int n_in,
                              void* d_out, int out_size, void* d_ws, size_t ws_size,
                              hipStream_t stream) {
  const int*   src  = (const int*)d_in[0];
  const float* Esrc = (const float*)d_in[1];
  const float* Etrg = (const float*)d_in[2];
  const float* Wih  = (const float*)d_in[3];
  const float* Whh  = (const float*)d_in[4];
  const float* bih  = (const float*)d_in[5];
  const float* bhh  = (const float*)d_in[6];
  const float* Wfc  = (const float*)d_in[7];
  const float* bfc  = (const float*)d_in[8];
  const float* Wh2o = (const float*)d_in[9];
  const float* bh2o = (const float*)d_in[10];
  const float* bout = (const float*)d_in[11];
  float* ws = (float*)d_ws;

  const size_t needET = (OFF_ET + (size_t)512 * 32000) * sizeof(float);
  const bool useET = (ws_size >= needET);
  float* etw = useET ? (ws + OFF_ET) : nullptr;

  (void)hipMemsetAsync(d_ws, 0, 32768, stream);   // reset barrier slots + flags

  (void)hipFuncSetAttribute(reinterpret_cast<const void*>(&s2s_mega),
                            hipFuncAttributeMaxDynamicSharedMemorySize, (int)LDS_BYTES);

  s2s_mega<<<dim3(NWG), dim3(TPB), LDS_BYTES, stream>>>(
      src, Esrc, Etrg, Wih, Whh, bih, bhh, Wfc, bfc, Wh2o, bh2o, bout,
      (float*)d_out, ws, etw, etw);
}

// Round 12
// 47725.668 us; speedup vs baseline: 1.0013x; 1.0013x over previous
//
#include <hip/hip_runtime.h>
#include <math.h>

#define NWG 256
#define TPB 512
#define AGT __HIP_MEMORY_SCOPE_AGENT

// ---- sizes ----
static constexpr int Bb = 32, Dd = 512, Tt = 32, Vv = 32000;
static constexpr int BD = Bb * Dd;                       // 16384
static constexpr float SCALE_INV = 0.04419417382415922f; // 1/sqrt(512)

// ---- ws layout (float offsets). Sync region = first 32 KB. ----
// H0/H1/Hl use PAIRED layout: element (b,k) at [b>>1]*1024 + k*2 + (b&1).
static constexpr size_t OFF_H0 = 8192;
static constexpr size_t OFF_H1 = OFF_H0 + 2 * (size_t)BD;
static constexpr size_t OFF_P  = OFF_H1 + 2 * (size_t)BD;             // [32][32][2048]
static constexpr size_t OFF_HL = OFF_P + (size_t)Tt * Bb * 2048;      // [32] paired
static constexpr size_t OFF_HD = OFF_HL + (size_t)Tt * BD;
static constexpr size_t OFF_OF = OFF_HD + BD;                          // [32][32][512]
static constexpr size_t OFF_CV = OFF_OF + (size_t)Tt * BD;             // [32][256]
static constexpr size_t OFF_CI = OFF_CV + 32 * 256;
static constexpr size_t OFF_ET = OFF_CI + 32 * 256;                    // ETb [16000][512][2]

// ---- LDS (floats). LSTM WGs: 48 weight rows + 16KB stage. G WGs overlay low region. ----
static constexpr int L_W   = 0;       // 48 x 576 slant-packed = 27648
static constexpr int L_H   = 27648;   // 4096 floats (16KB): H quarter-stage / scratch overlay
static constexpr int LDS_FLOATS = 31744;
static constexpr size_t LDS_BYTES = (size_t)LDS_FLOATS * 4;   // 126976
// G-WG overlay (weights region unused by G WGs):
static constexpr int G_HB  = 0;       // 2048 hidT block [64k][32b] swizzled (also noET rb)
static constexpr int G_GV  = 2048;    // 256
static constexpr int G_GI  = 2304;    // 256
static constexpr int G_TOK = 2560;    // 32
// CDEF / Y scratch overlay (inside L_H stage region, free between AB phases):
static constexpr int S_SC  = L_H;          // 512
static constexpr int S_RB  = L_H + 512;    // 1024
static constexpr int S_IB  = L_H + 1536;   // 512
static constexpr int S_RED = L_H + 2048;   // 16

__device__ __forceinline__ float sigm(float x) { return 1.0f / (1.0f + expf(-x)); }

// ---- IC-coherent (sc1) access: relaxed agent-scope atomics ----
__device__ __forceinline__ float ldcv(const float* p) {
  unsigned u = __hip_atomic_load((const unsigned*)p, __ATOMIC_RELAXED, AGT);
  return __builtin_bit_cast(float, u);
}
__device__ __forceinline__ void stcv(float* p, float v) {
  __hip_atomic_store((unsigned*)p, __builtin_bit_cast(unsigned, v), __ATOMIC_RELAXED, AGT);
}
__device__ __forceinline__ float2 ldcv2(const float* p) {
  unsigned long long u = __hip_atomic_load((const unsigned long long*)p, __ATOMIC_RELAXED, AGT);
  return __builtin_bit_cast(float2, u);
}
__device__ __forceinline__ void stcv2(float* p, float2 v) {
  __hip_atomic_store((unsigned long long*)p, __builtin_bit_cast(unsigned long long, v),
                     __ATOMIC_RELAXED, AGT);
}
__device__ __forceinline__ int ldcvi(const int* p) {
  return (int)__hip_atomic_load((const unsigned*)p, __ATOMIC_RELAXED, AGT);
}
__device__ __forceinline__ void stcvi(int* p, int v) {
  __hip_atomic_store((unsigned*)p, (unsigned)v, __ATOMIC_RELAXED, AGT);
}

__device__ __forceinline__ float wredsum(float v) {
#pragma unroll
  for (int off = 32; off > 0; off >>= 1) v += __shfl_xor(v, off, 64);
  return v;
}

// DPP rotate-reduce within each 16-lane row (pure VALU).
__device__ __forceinline__ float rowReduce16(float x) {
  int t;
  t = __builtin_amdgcn_update_dpp(0, __builtin_bit_cast(int, x), 0x121, 0xF, 0xF, false);
  x += __builtin_bit_cast(float, t);
  t = __builtin_amdgcn_update_dpp(0, __builtin_bit_cast(int, x), 0x122, 0xF, 0xF, false);
  x += __builtin_bit_cast(float, t);
  t = __builtin_amdgcn_update_dpp(0, __builtin_bit_cast(int, x), 0x124, 0xF, 0xF, false);
  x += __builtin_bit_cast(float, t);
  t = __builtin_amdgcn_update_dpp(0, __builtin_bit_cast(int, x), 0x128, 0xF, 0xF, false);
  x += __builtin_bit_cast(float, t);
  return x;
}

// ---- contention-free 2-level slot barrier (r8-proven, full 256 WGs) ----
__device__ __forceinline__ void gbar(unsigned* sb, unsigned& lg) {
  const unsigned tgt = lg + 1u;
  asm volatile("s_waitcnt vmcnt(0)" ::: "memory");
  __syncthreads();
  const int wg = (int)blockIdx.x;
  if (threadIdx.x < 64) {
    const int lane = (int)threadIdx.x;
    if (lane == 0)
      __hip_atomic_store(&sb[wg * 16], tgt, __ATOMIC_RELAXED, AGT);
    const int g = wg >> 5;
    if ((wg & 31) == 0) {                       // group leader
      if (lane < 32) {
        const unsigned* slot = &sb[(g * 32 + lane) * 16];
        while (__hip_atomic_load(slot, __ATOMIC_RELAXED, AGT) < tgt)
          __builtin_amdgcn_s_sleep(1);
      }
      if (lane == 0)
        __hip_atomic_store(&sb[4096 + g * 16], tgt, __ATOMIC_RELAXED, AGT);
    }
    if (lane < 8) {
      const unsigned* f = &sb[4096 + lane * 16];
      while (__hip_atomic_load(f, __ATOMIC_RELAXED, AGT) < tgt)
        __builtin_amdgcn_s_sleep(1);
    }
  }
  lg = tgt;
  __syncthreads();
}

__device__ __forceinline__ float blockMax(float v, float* red, int tid) {
#pragma unroll
  for (int off = 32; off > 0; off >>= 1) v = fmaxf(v, __shfl_xor(v, off, 64));
  if ((tid & 63) == 0) red[tid >> 6] = v;
  __syncthreads();
  float m = red[0];
#pragma unroll
  for (int i = 1; i < 8; ++i) m = fmaxf(m, red[i]);
  __syncthreads();
  return m;
}

__device__ __forceinline__ float blockSum(float v, float* red, int tid) {
  v = wredsum(v);
  if ((tid & 63) == 0) red[tid >> 6] = v;
  __syncthreads();
  float s = 0.f;
#pragma unroll
  for (int i = 0; i < 8; ++i) s += red[i];
  __syncthreads();
  return s;
}

// ---- stage 48 weight rows (4 cols/WG), slant-packed: rr = m*16 + q*4 + dl ----
__device__ __forceinline__ void stageW4(int wg, int tid, const float* __restrict__ Wih,
                                        const float* __restrict__ Whh, float* __restrict__ SMW) {
  for (int e = tid; e < 48 * 512; e += TPB) {
    const int k = e & 511, rr = e >> 9;
    const int m = rr >> 4, q = (rr >> 2) & 3, dl = rr & 3;
    const int j = q * 512 + wg * 4 + dl;
    const float* srcp = (m == 0) ? (Whh + (size_t)j * 512)
                     : (m == 1) ? (Wih + (size_t)2048 * 512 + (size_t)j * 512)
                                : (Whh + (size_t)2048 * 512 + (size_t)j * 512);
    SMW[rr * 576 + (k >> 5) * 36 + (k & 31)] = srcp[k];
  }
  __syncthreads();
}

// ---- WG-private build of ETb[v/2][k][2] (panel [wg*128, +128)); sc1 stores ----
__device__ __forceinline__ void buildETb(int wg, int tid, const float* __restrict__ Etrg,
                                         float* __restrict__ ETb, float* __restrict__ SM) {
  if (wg < 250) {
    for (int tile = 0; tile < 8; ++tile) {
      const int tv = tile >> 2, tk = tile & 3;
      __syncthreads();
      for (int e = tid; e < 64 * 128; e += TPB) {
        const int vl = e >> 7, kl = e & 127;
        SM[vl * 129 + kl] = Etrg[(size_t)(wg * 128 + tv * 64 + vl) * 512 + tk * 128 + kl];
      }
      __syncthreads();
      for (int e = tid; e < 32 * 128; e += TPB) {
        const int vp = e >> 7, kl = e & 127;
        const int v = wg * 128 + tv * 64 + vp * 2;
        const int k = tk * 128 + kl;
        float2 val = make_float2(SM[(vp * 2) * 129 + kl], SM[(vp * 2 + 1) * 129 + kl]);
        stcv2(ETb + ((size_t)(v >> 1) * 512 + k) * 2, val);
      }
    }
    __syncthreads();
  }
}

// ---- phaseAB4 helpers: quarter-staged H (16 KB), vmcnt(0)-only waits ----
__device__ __forceinline__ void ld2q(const float* base, int tid, float4 s[2]) {
  const float* p0 = base + tid * 4;
  const float* p1 = base + 2048 + tid * 4;
  asm volatile("global_load_dwordx4 %0, %1, off sc1" : "=v"(s[0]) : "v"(p0));
  asm volatile("global_load_dwordx4 %0, %1, off sc1" : "=v"(s[1]) : "v"(p1));
}
__device__ __forceinline__ void stage2(char* LHc, int tid, const float4 s[2]) {
  int byA = tid * 16;         byA ^= ((byA >> 8) & 7) << 4;
  int byB = (512 + tid) * 16; byB ^= ((byB >> 8) & 7) << 4;
  *(float4*)(LHc + byA) = s[0];
  *(float4*)(LHc + byB) = s[1];
}
__device__ __forceinline__ void readHq4(const char* LHc, int b2l, int kc, float4 hq[16]) {
#pragma unroll
  for (int i = 0; i < 16; ++i) {
    int byte = b2l * 4096 + kc * 256 + i * 16;
    byte ^= ((byte >> 8) & 7) << 4;
    hq[i] = *(const float4*)(LHc + byte);
  }
}
// dot of slant-packed W row rr with paired H fragments -> float2 (b even, b odd)
__device__ __forceinline__ void dotMQ(const float* __restrict__ SMW, int rr, int kc,
                                      const float4* __restrict__ hq, float2& acc) {
  const float4* wr = (const float4*)(SMW + rr * 576 + kc * 36);
#pragma unroll
  for (int i2 = 0; i2 < 8; ++i2) {
    const float4 wv = wr[i2];
    const float4 hA = hq[i2 * 2], hB = hq[i2 * 2 + 1];
    acc.x = fmaf(wv.x, hA.x, acc.x); acc.y = fmaf(wv.x, hA.y, acc.y);
    acc.x = fmaf(wv.y, hA.z, acc.x); acc.y = fmaf(wv.y, hA.w, acc.y);
    acc.x = fmaf(wv.z, hB.x, acc.x); acc.y = fmaf(wv.z, hB.y, acc.y);
    acc.x = fmaf(wv.w, hB.z, acc.x); acc.y = fmaf(wv.w, hB.w, acc.y);
  }
}

// ---- merged LSTM phase, 4 cols/WG (WGs 0..127). tid = b2*32 + dh*16 + kc. ----
__device__ __forceinline__ void phaseAB4(
    int wg, int tid, bool doA, bool doB,
    const float* __restrict__ H0r, float* __restrict__ H0w,
    const float* __restrict__ H1r, float* __restrict__ H1w,
    float* __restrict__ HlP, const float* __restrict__ Pp,
    const float bs1v[2][4], const float* __restrict__ SMW, float* __restrict__ LH,
    float c0[2][2], float c1[2][2])
{
  const int b2 = tid >> 5, dh = (tid >> 4) & 1, kc = tid & 15;
  const int q4 = b2 >> 2, b2l = b2 & 3;
  char* LHc = (char*)LH;
  float4 s[2], hq[16];

  // ---- H0: 4 quarter-rounds (16 KB each), vmcnt(0)-only ----
  ld2q(H0r, tid, s);
#pragma unroll
  for (int qq = 0; qq < 4; ++qq) {
    asm volatile("s_waitcnt vmcnt(0)" ::: "memory");
    __builtin_amdgcn_sched_barrier(0);
    stage2(LHc, tid, s);
    if (qq < 3) ld2q(H0r + (qq + 1) * 4096, tid, s);
    else if (doB) ld2q(H1r, tid, s);         // first H1 quarter flies under dots
    __syncthreads();
    if (q4 == qq) readHq4(LHc, b2l, kc, hq);
    __syncthreads();
  }

  float2 a2[2][12];
#pragma unroll
  for (int dlx = 0; dlx < 2; ++dlx)
#pragma unroll
    for (int j = 0; j < 12; ++j) a2[dlx][j] = make_float2(0.f, 0.f);

  if (doA) {
#pragma unroll
    for (int dlx = 0; dlx < 2; ++dlx)
#pragma unroll
      for (int q = 0; q < 4; ++q)
        dotMQ(SMW, q * 4 + dh * 2 + dlx, kc, hq, a2[dlx][q]);          // Whh0.H0
  }
  if (doB) {
#pragma unroll
    for (int dlx = 0; dlx < 2; ++dlx)
#pragma unroll
      for (int q = 0; q < 4; ++q)
        dotMQ(SMW, 16 + q * 4 + dh * 2 + dlx, kc, hq, a2[dlx][4 + q]); // Wih1.H0
    // ---- H1: 4 quarter-rounds ----
#pragma unroll
    for (int qq = 0; qq < 4; ++qq) {
      asm volatile("s_waitcnt vmcnt(0)" ::: "memory");
      __builtin_amdgcn_sched_barrier(0);
      stage2(LHc, tid, s);
      if (qq < 3) ld2q(H1r + (qq + 1) * 4096, tid, s);
      __syncthreads();
      if (q4 == qq) readHq4(LHc, b2l, kc, hq);
      __syncthreads();
    }
#pragma unroll
    for (int dlx = 0; dlx < 2; ++dlx)
#pragma unroll
      for (int q = 0; q < 4; ++q)
        dotMQ(SMW, 32 + q * 4 + dh * 2 + dlx, kc, hq, a2[dlx][8 + q]); // Whh1.H1
  }

#pragma unroll
  for (int dlx = 0; dlx < 2; ++dlx)
#pragma unroll
    for (int j = 0; j < 12; ++j) {
      if (j < 4 ? !doA : !doB) continue;
      a2[dlx][j].x = rowReduce16(a2[dlx][j].x);
      a2[dlx][j].y = rowReduce16(a2[dlx][j].y);
    }

  if (kc == 0) {                      // 32 lanes own (b2, dh); 2 cols each
#pragma unroll
    for (int dlx = 0; dlx < 2; ++dlx) {
      const int d = (wg << 2) | (dh << 1) | dlx;
      if (doA) {
#pragma unroll
        for (int p = 0; p < 2; ++p) {
          const int b = b2 * 2 + p;
          const float* pb = Pp + b * 2048 + d;
          const float gi = (p ? a2[dlx][0].y : a2[dlx][0].x) + pb[0];
          const float gf = (p ? a2[dlx][1].y : a2[dlx][1].x) + pb[512];
          const float gg = (p ? a2[dlx][2].y : a2[dlx][2].x) + pb[1024];
          const float go = (p ? a2[dlx][3].y : a2[dlx][3].x) + pb[1536];
          c0[dlx][p] = sigm(gf) * c0[dlx][p] + sigm(gi) * tanhf(gg);
          stcv(H0w + b2 * 1024 + d * 2 + p, sigm(go) * tanhf(c0[dlx][p]));
        }
      }
      if (doB) {
#pragma unroll
        for (int p = 0; p < 2; ++p) {
          const float gi = (p ? a2[dlx][4].y : a2[dlx][4].x) + (p ? a2[dlx][8].y  : a2[dlx][8].x)  + bs1v[dlx][0];
          const float gf = (p ? a2[dlx][5].y : a2[dlx][5].x) + (p ? a2[dlx][9].y  : a2[dlx][9].x)  + bs1v[dlx][1];
          const float gg = (p ? a2[dlx][6].y : a2[dlx][6].x) + (p ? a2[dlx][10].y : a2[dlx][10].x) + bs1v[dlx][2];
          const float go = (p ? a2[dlx][7].y : a2[dlx][7].x) + (p ? a2[dlx][11].y : a2[dlx][11].x) + bs1v[dlx][3];
          c1[dlx][p] = sigm(gf) * c1[dlx][p] + sigm(gi) * tanhf(gg);
          const float hn = sigm(go) * tanhf(c1[dlx][p]);
          stcv(H1w + b2 * 1024 + d * 2 + p, hn);
          if (HlP) stcv(HlP + b2 * 1024 + d * 2 + p, hn);
        }
      }
    }
  }
}

// ---- fused fc + attention + context + h2o for one batch row (WGs 0..31) ----
__device__ __forceinline__ void phaseCDEF(int b, int tid, const float* __restrict__ H1c,
                          const float* __restrict__ Wfc, const float* __restrict__ bfc,
                          const int* __restrict__ src, const float* __restrict__ Esrc,
                          const float* __restrict__ Wh2o, const float* __restrict__ bh2o,
                          float* __restrict__ hD, float* sc, float* rb, int* ib, float* red)
{
  rb[tid] = ldcv(H1c + (b >> 1) * 1024 + tid * 2 + (b & 1));  // paired layout
  ib[tid] = src[b * 512 + tid];
  __syncthreads();
  const int w = tid >> 6, lane = tid & 63;
  for (int d = w; d < 512; d += 8) {            // fc_out
    const float* wr = Wfc + (size_t)d * 512;
    float p = 0.f;
#pragma unroll
    for (int i = 0; i < 8; ++i) p = fmaf(rb[lane * 8 + i], wr[lane * 8 + i], p);
    p = wredsum(p);
    if (lane == 0) rb[512 + d] = p + bfc[d];
  }
  __syncthreads();
  for (int s = w; s < 512; s += 8) {            // scores
    const float* er = Esrc + (size_t)ib[s] * 512;
    float p = 0.f;
#pragma unroll
    for (int i = 0; i < 8; ++i) p = fmaf(rb[512 + lane * 8 + i], er[lane * 8 + i], p);
    p = wredsum(p);
    if (lane == 0) sc[s] = p * SCALE_INV;
  }
  __syncthreads();
  const float mx = blockMax(sc[tid], red, tid);
  const float e = expf(sc[tid] - mx);
  sc[tid] = e;
  const float sum = blockSum(e, red, tid);
  const float inv = 1.0f / sum;
  float acc = 0.f;
#pragma unroll 4
  for (int s = 0; s < 512; ++s) acc = fmaf(sc[s], Esrc[(size_t)ib[s] * 512 + tid], acc);
  rb[tid] = acc * inv;                          // ctx
  __syncthreads();
  for (int d = w; d < 512; d += 8) {            // h2o + relu
    const float* wr = Wh2o + (size_t)d * 1024;
    float p = 0.f;
#pragma unroll
    for (int i = 0; i < 8; ++i) p = fmaf(rb[512 + lane * 8 + i], wr[lane * 8 + i], p);
#pragma unroll
    for (int i = 0; i < 8; ++i) p = fmaf(rb[lane * 8 + i], wr[512 + lane * 8 + i], p);
    p = wredsum(p);
    if (lane == 0) stcv(hD + (size_t)b * 512 + d, fmaxf(p + bh2o[d], 0.f));
  }
  __syncthreads();
}

// ---- logits panel chunk: 256 v per G WG, k-half per chunk, all 32 b ----
__device__ __forceinline__ void phaseG_panelC(int wgG, int tid, int chunk, float (*acc)[4],
                              const float* __restrict__ hD, const float* __restrict__ ETb,
                              const float* __restrict__ bout, float* __restrict__ candV,
                              int* __restrict__ candI, float* __restrict__ hblk,
                              float* __restrict__ gv, int* __restrict__ gi)
{
  if (wgG >= 125) return;
  if (chunk == 0) {
#pragma unroll
    for (int a = 0; a < 4; ++a)
#pragma unroll
      for (int b = 0; b < 4; ++b) acc[a][b] = 0.f;
  }
  const int vp = tid >> 3, bh = tid & 7;
  const int v0 = wgG * 256 + vp * 4;
  const float* epA = ETb + (size_t)(v0 >> 1) * 1024 + chunk * 512;
  const float* epB = epA + 1024;
  const int fk = tid & 63, fb0 = tid >> 6;
  char* hb = (char*)hblk;

  for (int blk = 0; blk < 4; ++blk) {
    const int kb = chunk * 256 + blk * 64;
    __syncthreads();
#pragma unroll
    for (int i = 0; i < 4; ++i) {
      const int b = fb0 + i * 8;
      const float hv = ldcv(hD + (size_t)b * 512 + kb + fk);
      const int byte = fk * 128 + (((b >> 2) * 16) ^ ((fk & 7) << 4)) + ((b & 3) << 2);
      *(float*)(hb + byte) = hv;
    }
    __syncthreads();
#pragma unroll 8
    for (int kk = 0; kk < 64; kk += 2) {
      const float4 eA = *(const float4*)epA; epA += 4;
      const float4 eB = *(const float4*)epB; epB += 4;
      const float4 h0 = *(const float4*)(hb + kk * 128 + ((bh * 16) ^ ((kk & 7) << 4)));
      const float4 h1 = *(const float4*)(hb + (kk + 1) * 128 + ((bh * 16) ^ (((kk + 1) & 7) << 4)));
#pragma unroll
      for (int bj = 0; bj < 4; ++bj) {
        const float h0v = (bj == 0) ? h0.x : (bj == 1) ? h0.y : (bj == 2) ? h0.z : h0.w;
        const float h1v = (bj == 0) ? h1.x : (bj == 1) ? h1.y : (bj == 2) ? h1.z : h1.w;
        acc[0][bj] = fmaf(eA.x, h0v, acc[0][bj]);
        acc[0][bj] = fmaf(eA.z, h1v, acc[0][bj]);
        acc[1][bj] = fmaf(eA.y, h0v, acc[1][bj]);
        acc[1][bj] = fmaf(eA.w, h1v, acc[1][bj]);
        acc[2][bj] = fmaf(eB.x, h0v, acc[2][bj]);
        acc[2][bj] = fmaf(eB.z, h1v, acc[2][bj]);
        acc[3][bj] = fmaf(eB.y, h0v, acc[3][bj]);
        acc[3][bj] = fmaf(eB.w, h1v, acc[3][bj]);
      }
    }
  }
  if (chunk == 1) {
    const float bo[4] = {bout[v0], bout[v0 + 1], bout[v0 + 2], bout[v0 + 3]};
    const int w = tid >> 6;
#pragma unroll
    for (int bj = 0; bj < 4; ++bj) {
      float bv = acc[0][bj] + bo[0]; int bi = v0;
#pragma unroll
      for (int vj = 1; vj < 4; ++vj) {
        const float vv = acc[vj][bj] + bo[vj];
        if (vv > bv) { bv = vv; bi = v0 + vj; }
      }
#pragma unroll
      for (int off = 8; off < 64; off <<= 1) {
        const float ov = __shfl_xor(bv, off, 64); const int oi = __shfl_xor(bi, off, 64);
        if (ov > bv || (ov == bv && oi < bi)) { bv = ov; bi = oi; }
      }
      if ((tid & 63) < 8) {
        gv[(bh * 4 + bj) * 8 + w] = bv;
        gi[(bh * 4 + bj) * 8 + w] = bi;
      }
    }
    __syncthreads();
    if (tid < 32) {
      float bv = -INFINITY; int bi = 0;
      for (int w2 = 0; w2 < 8; ++w2) {
        const float vv = gv[tid * 8 + w2]; const int ii = gi[tid * 8 + w2];
        if (vv > bv || (vv == bv && ii < bi)) { bv = vv; bi = ii; }
      }
      stcv(candV + (size_t)tid * 256 + wgG, bv);
      stcvi(candI + tid * 256 + wgG, bi);
    }
    __syncthreads();
  }
}

// ---- fallback logits (row-major Etrg): 250 v per G WG, 32 b sequential ----
__device__ __forceinline__ void phaseG_noET2(int wgG, int tid, const float* __restrict__ hD,
                             const float* __restrict__ Etrg, const float* __restrict__ bout,
                             float* __restrict__ candV, int* __restrict__ candI,
                             float* rb, float* gv, int* gi)
{
  const int w = tid >> 6, lane = tid & 63;
  for (int b = 0; b < 32; ++b) {
    __syncthreads();
    rb[tid & 511] = ldcv(hD + (size_t)b * 512 + (tid & 511));
    __syncthreads();
    float bv = -INFINITY; int bi = 0x7fffffff;
    for (int v = wgG * 250 + w; v < wgG * 250 + 250; v += 8) {
      const float* er = Etrg + (size_t)v * 512;
      float p = 0.f;
#pragma unroll
      for (int i = 0; i < 8; ++i) p = fmaf(rb[lane * 8 + i], er[lane * 8 + i], p);
      p = wredsum(p);
      p += bout[v];
      if (p > bv || (p == bv && v < bi)) { bv = p; bi = v; }
    }
    if (lane == 0) { gv[w] = bv; gi[w] = bi; }
    __syncthreads();
    if (tid == 0) {
      float fv = -INFINITY; int fi = 0x7fffffff;
      for (int w2 = 0; w2 < 8; ++w2)
        if (gv[w2] > fv || (gv[w2] == fv && gi[w2] < fi)) { fv = gv[w2]; fi = gi[w2]; }
      stcv(candV + (size_t)b * 256 + wgG, fv);
      stcvi(candI + b * 256 + wgG, fi);
    }
  }
  __syncthreads();
}

// ---- token argmax finalize + this G WG's 16 rows of P[t+1] ----
__device__ __forceinline__ void phaseHP_G(int wgG, int tid, int t, int nslot,
                          const float* __restrict__ candV, const int* __restrict__ candI,
                          const float* __restrict__ Etrg, const float* __restrict__ Wih,
                          const float* __restrict__ bih, const float* __restrict__ bhh,
                          float* __restrict__ P, float* __restrict__ out, int* tokL)
{
  {
    const int b = tid >> 4, sl = tid & 15;
    float bv = -INFINITY; int bi = 0x7fffffff;
    for (int s = sl; s < nslot; s += 16) {
      const float vv = ldcv(candV + (size_t)b * 256 + s);
      const int ii = ldcvi(candI + b * 256 + s);
      if (vv > bv || (vv == bv && ii < bi)) { bv = vv; bi = ii; }
    }
#pragma unroll
    for (int off = 1; off < 16; off <<= 1) {
      const float ov = __shfl_xor(bv, off, 64); const int oi = __shfl_xor(bi, off, 64);
      if (ov > bv || (ov == bv && oi < bi)) { bv = ov; bi = oi; }
    }
    if (sl == 0) {
      tokL[b] = bi;
      if (wgG == 0) stcv(out + b * 32 + t, (float)bi);   // tokens[:,1:][b][t]
    }
  }
  __syncthreads();
  if (t < 31) {
    const int w = tid >> 6, lane = tid & 63;
    for (int jj = w; jj < 16; jj += 8) {
      const int j = wgG * 16 + jj;
      const float* wr = Wih + (size_t)j * 512;
      const float bsum = bih[j] + bhh[j];
      for (int b = 0; b < 32; ++b) {
        const float* er = Etrg + (size_t)tokL[b] * 512;
        float p = 0.f;
#pragma unroll
        for (int i = 0; i < 8; ++i) p = fmaf(er[lane * 8 + i], wr[lane * 8 + i], p);
        p = wredsum(p);
        if (lane == 0) stcv(P + ((size_t)(t + 1) * 32 + b) * 2048 + j, p + bsum);
      }
    }
  }
  __syncthreads();
}

// ---- outfc[p][b][:] = Hlast[p][b] @ Wfc^T + bfc (paired Hl; 1 unit/WG) ----
__device__ __forceinline__ void phaseX(int wg, int tid, const float* __restrict__ Hl,
                       const float* __restrict__ Wfc,
                       const float* __restrict__ bfc, float* __restrict__ oF)
{
  const int p = wg >> 3, bq = wg & 7;
  const int w = tid >> 6, lane = tid & 63;
  for (int u = w; u < 1024; u += 8) {
    const int b2 = bq * 2 + (u >> 9), d = u & 511;
    const float* hr = Hl + (size_t)p * BD + b2 * 1024;
    const float* wr = Wfc + (size_t)d * 512;
    float ax = 0.f, ay = 0.f;
#pragma unroll
    for (int i = 0; i < 8; ++i) {
      const float2 hv = ldcv2(hr + (lane * 8 + i) * 2);
      const float wv = wr[lane * 8 + i];
      ax = fmaf(hv.x, wv, ax);
      ay = fmaf(hv.y, wv, ay);
    }
    ax = wredsum(ax); ay = wredsum(ay);
    if (lane == 0) {
      stcv(oF + ((size_t)p * 32 + b2 * 2    ) * 512 + d, ax + bfc[d]);
      stcv(oF + ((size_t)p * 32 + b2 * 2 + 1) * 512 + d, ay + bfc[d]);
    }
  }
}

// ---- final attn rows: 4 per WG ----
__device__ __forceinline__ void phaseY(int wg, int tid, const float* __restrict__ oF,
                       const int* __restrict__ src,
                       const float* __restrict__ Esrc, float* __restrict__ out,
                       float* sc, float* rb, int* ib, float* red)
{
  for (int r = 0; r < 4; ++r) {
    const int id = wg * 4 + r;
    const int b = id >> 5, p = id & 31;
    __syncthreads();
    rb[tid] = ldcv(oF + ((size_t)p * 32 + b) * 512 + tid);
    ib[tid] = src[b * 512 + tid];
    __syncthreads();
    const int w = tid >> 6, lane = tid & 63;
    for (int s = w; s < 512; s += 8) {
      const float* er = Esrc + (size_t)ib[s] * 512;
      float acc = 0.f;
#pragma unroll
      for (int i = 0; i < 8; ++i) acc = fmaf(rb[lane * 8 + i], er[lane * 8 + i], acc);
      acc = wredsum(acc);
      if (lane == 0) sc[s] = acc * SCALE_INV;
    }
    __syncthreads();
    const float mx = blockMax(sc[tid], red, tid);
    const float e = expf(sc[tid] - mx);
    const float sum = blockSum(e, red, tid);
    out[1024 + ((size_t)b * 32 + p) * 512 + tid] = e / sum;
  }
}

extern "C" __global__ void __launch_bounds__(TPB, 1)
s2s_mega(const int* __restrict__ src, const float* __restrict__ Esrc, const float* __restrict__ Etrg,
         const float* __restrict__ Wih, const float* __restrict__ Whh,
         const float* __restrict__ bih, const float* __restrict__ bhh,
         const float* __restrict__ Wfc, const float* __restrict__ bfc,
         const float* __restrict__ Wh2o, const float* __restrict__ bh2o,
         const float* __restrict__ bout, float* __restrict__ out,
         float* __restrict__ ws, const float* __restrict__ ET, float* __restrict__ ETw)
{
  extern __shared__ float SM[];
  float* SMW = SM + L_W;
  float* LH  = SM + L_H;
  // overlays
  float* hblk = SM + G_HB;
  float* gv  = SM + G_GV;
  int*   gi  = (int*)(SM + G_GI);
  int*   tokG = (int*)(SM + G_TOK);
  float* scY = SM + S_SC;
  float* rbY = SM + S_RB;
  int*   ibY = (int*)(SM + S_IB);
  float* redY = SM + S_RED;

  unsigned* sb = (unsigned*)ws;
  float* H0 = ws + OFF_H0;
  float* H1 = ws + OFF_H1;
  float* P  = ws + OFF_P;
  float* Hl = ws + OFF_HL;
  float* hD = ws + OFF_HD;
  float* oF = ws + OFF_OF;
  float* cV = ws + OFF_CV;
  int*   cI = (int*)(ws + OFF_CI);

  const int wg = blockIdx.x, tid = threadIdx.x;
  const bool useET = (ET != nullptr);
  unsigned lg = 0u;
  float c0[2][2] = {{0.f, 0.f}, {0.f, 0.f}};
  float c1[2][2] = {{0.f, 0.f}, {0.f, 0.f}};
  float accG[4][4];
  float bs1v[2][4] = {{0.f,0.f,0.f,0.f},{0.f,0.f,0.f,0.f}};

  if (wg < 128) {       // layer-1 bias sums for this WG's 4 columns
    const int dh = (tid >> 4) & 1;
#pragma unroll
    for (int dlx = 0; dlx < 2; ++dlx) {
      const int d = (wg << 2) | (dh << 1) | dlx;
#pragma unroll
      for (int q = 0; q < 4; ++q)
        bs1v[dlx][q] = bih[2048 + q * 512 + d] + bhh[2048 + q * 512 + d];
    }
  }

  // ---- setup: zero carried H state ----
  {
    const int gid = wg * TPB + tid;
    if (gid < BD) stcv(H0 + gid, 0.f);
    else if (gid < 2 * BD) stcv(H1 + gid - BD, 0.f);
  }
  // ---- P[0] = emb([SOS]) @ Wih0^T + biases (all 256 WGs, 8 rows each) ----
  {
    const int w = tid >> 6, lane = tid & 63;
    const int q = w >> 1, dl = w & 1;
    const int j = q * 512 + wg * 2 + dl;
    const float* er = Etrg + 512;               // token 1 ([SOS])
    const float* wr = Wih + (size_t)j * 512;
    float p = 0.f;
#pragma unroll
    for (int i = 0; i < 8; ++i) p = fmaf(er[lane * 8 + i], wr[lane * 8 + i], p);
    p = wredsum(p);
    p += bih[j] + bhh[j];
    if (lane < 32) stcv(P + (size_t)lane * 2048 + j, p);
  }
  if (ETw) buildETb(wg, tid, Etrg, ETw, SM);
  if (wg < 128) stageW4(wg, tid, Wih, Whh, SMW);
  gbar(sb, lg);

  int cur0 = 0, cur1 = 0;
  for (int t = 0; t < 32; ++t) {
    for (int k = 0; k <= t + 1; ++k) {
      const bool doA = (k <= t), doB = (k >= 1);
      if (wg < 128) {
        float* HlP = (t == 31 && doB) ? (Hl + (size_t)(k - 1) * BD) : nullptr;
        const int kp = (k < 32) ? k : 31;
        phaseAB4(wg, tid, doA, doB,
                 H0 + (size_t)cur0 * BD, H0 + (size_t)(cur0 ^ 1) * BD,
                 H1 + (size_t)cur1 * BD, H1 + (size_t)(cur1 ^ 1) * BD,
                 HlP, P + (size_t)kp * Bb * 2048, bs1v, SMW, LH, c0, c1);
      } else {
        const int wgG = wg - 128;
        if (useET) {
          if (t >= 2 && k == 0) {
            phaseG_panelC(wgG, tid, 0, accG, hD, ET, bout, cV, cI, hblk, gv, gi);
            if (t == 2) phaseG_panelC(wgG, tid, 1, accG, hD, ET, bout, cV, cI, hblk, gv, gi);
          }
          if (t >= 3 && k == 1)
            phaseG_panelC(wgG, tid, 1, accG, hD, ET, bout, cV, cI, hblk, gv, gi);
          if (t == 2 && k == 1)
            phaseHP_G(wgG, tid, 1, 125, cV, cI, Etrg, Wih, bih, bhh, P, out, tokG);
          if (t >= 3 && k == 2)
            phaseHP_G(wgG, tid, t - 1, 125, cV, cI, Etrg, Wih, bih, bhh, P, out, tokG);
        } else {
          if (t >= 2 && k == 0)
            phaseG_noET2(wgG, tid, hD, Etrg, bout, cV, cI, hblk, gv, gi);
          if (t == 2 && k == 1)
            phaseHP_G(wgG, tid, 1, 128, cV, cI, Etrg, Wih, bih, bhh, P, out, tokG);
          if (t >= 3 && k == 2)
            phaseHP_G(wgG, tid, t - 1, 128, cV, cI, Etrg, Wih, bih, bhh, P, out, tokG);
        }
      }
      gbar(sb, lg);
      if (doA) cur0 ^= 1;
      if (doB) cur1 ^= 1;
    }
    if (wg < 32) phaseCDEF(wg, tid, H1 + (size_t)cur1 * BD, Wfc, bfc, src, Esrc,
                           Wh2o, bh2o, hD, scY, rbY, ibY, redY);
    gbar(sb, lg);
    if (t == 0) {       // bootstrap: G(0) + HP(0) standalone
      if (wg >= 128) {
        const int wgG = wg - 128;
        if (useET) {
          phaseG_panelC(wgG, tid, 0, accG, hD, ET, bout, cV, cI, hblk, gv, gi);
          phaseG_panelC(wgG, tid, 1, accG, hD, ET, bout, cV, cI, hblk, gv, gi);
        } else {
          phaseG_noET2(wgG, tid, hD, Etrg, bout, cV, cI, hblk, gv, gi);
        }
      }
      gbar(sb, lg);
      if (wg >= 128)
        phaseHP_G(wg - 128, tid, 0, useET ? 125 : 128, cV, cI, Etrg, Wih, bih, bhh, P, out, tokG);
      gbar(sb, lg);
    }
  }
  // ---- tail: X + G(31); then HP(31) token finalize + Y ----
  phaseX(wg, tid, Hl, Wfc, bfc, oF);
  if (wg >= 128) {
    const int wgG = wg - 128;
    if (useET) {
      phaseG_panelC(wgG, tid, 0, accG, hD, ET, bout, cV, cI, hblk, gv, gi);
      phaseG_panelC(wgG, tid, 1, accG, hD, ET, bout, cV, cI, hblk, gv, gi);
    } else {
      phaseG_noET2(wgG, tid, hD, Etrg, bout, cV, cI, hblk, gv, gi);
    }
  }
  gbar(sb, lg);
  if (wg >= 128)
    phaseHP_G(wg - 128, tid, 31, useET ? 125 : 128, cV, cI, Etrg, Wih, bih, bhh, P, out, tokG);
  phaseY(wg, tid, oF, src, Esrc, out, scY, rbY, ibY, redY);
}

extern "C" void kernel_launch(void* const* d_in, const int* in_sizes, int n_in,
                              void* d_out, int out_size, void* d_ws, size_t ws_size,
                              hipStream_t stream) {
  const int*   src  = (const int*)d_in[0];
  const float* Esrc = (const float*)d_in[1];
  const float* Etrg = (const float*)d_in[2];
  const float* Wih  = (const float*)d_in[3];
  const float* Whh  = (const float*)d_in[4];
  const float* bih  = (const float*)d_in[5];
  const float* bhh  = (const float*)d_in[6];
  const float* Wfc  = (const float*)d_in[7];
  const float* bfc  = (const float*)d_in[8];
  const float* Wh2o = (const float*)d_in[9];
  const float* bh2o = (const float*)d_in[10];
  const float* bout = (const float*)d_in[11];
  float* ws = (float*)d_ws;

  const size_t needET = (OFF_ET + (size_t)512 * 32000) * sizeof(float);
  const bool useET = (ws_size >= needET);
  float* etw = useET ? (ws + OFF_ET) : nullptr;

  (void)hipMemsetAsync(d_ws, 0, 32768, stream);   // reset barrier slots + flags

  (void)hipFuncSetAttribute(reinterpret_cast<const void*>(&s2s_mega),
                            hipFuncAttributeMaxDynamicSharedMemorySize, (int)LDS_BYTES);

  s2s_mega<<<dim3(NWG), dim3(TPB), LDS_BYTES, stream>>>(
      src, Esrc, Etrg, Wih, Whh, bih, bhh, Wfc, bfc, Wh2o, bh2o, bout,
      (float*)d_out, ws, etw, etw);
}

// Round 13
// 46451.974 us; speedup vs baseline: 1.0287x; 1.0274x over previous
//
#include <hip/hip_runtime.h>
#include <math.h>

#define NWG 256
#define TPB 512
#define AGT __HIP_MEMORY_SCOPE_AGENT

// ---- sizes ----
static constexpr int Bb = 32, Dd = 512, Tt = 32, Vv = 32000;
static constexpr int BD = Bb * Dd;                       // 16384
static constexpr float SCALE_INV = 0.04419417382415922f; // 1/sqrt(512)

// ---- ws layout (float offsets). Sync region = first 32 KB. ----
// H0/H1/Hl use PAIRED layout: element (b,k) at [b>>1]*1024 + k*2 + (b&1).
static constexpr size_t OFF_H0 = 8192;
static constexpr size_t OFF_H1 = OFF_H0 + 2 * (size_t)BD;
static constexpr size_t OFF_P  = OFF_H1 + 2 * (size_t)BD;             // [32][32][2048]
static constexpr size_t OFF_HL = OFF_P + (size_t)Tt * Bb * 2048;      // [32] paired
static constexpr size_t OFF_HD = OFF_HL + (size_t)Tt * BD;
static constexpr size_t OFF_OF = OFF_HD + BD;                          // [32][32][512]
static constexpr size_t OFF_CV = OFF_OF + (size_t)Tt * BD;             // [32][256]
static constexpr size_t OFF_CI = OFF_CV + 32 * 256;
static constexpr size_t OFF_ET = OFF_CI + 32 * 256;                    // ETb [16000][512][2]

// ---- LDS (floats). LSTM WGs: 48 weight rows + 16KB stage. G WGs overlay low region. ----
static constexpr int L_W   = 0;       // 48 x 576 slant-packed = 27648
static constexpr int L_H   = 27648;   // 4096 floats (16KB): H quarter-stage / scratch overlay
static constexpr int LDS_FLOATS = 31744;
static constexpr size_t LDS_BYTES = (size_t)LDS_FLOATS * 4;   // 126976
// G-WG overlay (weights region unused by G WGs after setup):
static constexpr int G_HB  = 0;       // 2048 hidT block [64k][32b] swizzled (also noET rb)
static constexpr int G_GV  = 2048;    // 256
static constexpr int G_GI  = 2304;    // 256
static constexpr int G_TOK = 2560;    // 32
static constexpr int G_ACC = 4096;    // 16 x 520 = 8320: explicit acc carry (padded, conflict-free)
// CDEF / Y scratch overlay (inside L_H stage region, free between AB phases):
static constexpr int S_SC  = L_H;          // 512
static constexpr int S_RB  = L_H + 512;    // 1024
static constexpr int S_IB  = L_H + 1536;   // 512
static constexpr int S_RED = L_H + 2048;   // 16

__device__ __forceinline__ float sigm(float x) { return 1.0f / (1.0f + expf(-x)); }

// ---- IC-coherent (sc1) access: relaxed agent-scope atomics ----
__device__ __forceinline__ float ldcv(const float* p) {
  unsigned u = __hip_atomic_load((const unsigned*)p, __ATOMIC_RELAXED, AGT);
  return __builtin_bit_cast(float, u);
}
__device__ __forceinline__ void stcv(float* p, float v) {
  __hip_atomic_store((unsigned*)p, __builtin_bit_cast(unsigned, v), __ATOMIC_RELAXED, AGT);
}
__device__ __forceinline__ float2 ldcv2(const float* p) {
  unsigned long long u = __hip_atomic_load((const unsigned long long*)p, __ATOMIC_RELAXED, AGT);
  return __builtin_bit_cast(float2, u);
}
__device__ __forceinline__ void stcv2(float* p, float2 v) {
  __hip_atomic_store((unsigned long long*)p, __builtin_bit_cast(unsigned long long, v),
                     __ATOMIC_RELAXED, AGT);
}
__device__ __forceinline__ int ldcvi(const int* p) {
  return (int)__hip_atomic_load((const unsigned*)p, __ATOMIC_RELAXED, AGT);
}
__device__ __forceinline__ void stcvi(int* p, int v) {
  __hip_atomic_store((unsigned*)p, (unsigned)v, __ATOMIC_RELAXED, AGT);
}

__device__ __forceinline__ float wredsum(float v) {
#pragma unroll
  for (int off = 32; off > 0; off >>= 1) v += __shfl_xor(v, off, 64);
  return v;
}

// DPP rotate-reduce within each 16-lane row (pure VALU).
__device__ __forceinline__ float rowReduce16(float x) {
  int t;
  t = __builtin_amdgcn_update_dpp(0, __builtin_bit_cast(int, x), 0x121, 0xF, 0xF, false);
  x += __builtin_bit_cast(float, t);
  t = __builtin_amdgcn_update_dpp(0, __builtin_bit_cast(int, x), 0x122, 0xF, 0xF, false);
  x += __builtin_bit_cast(float, t);
  t = __builtin_amdgcn_update_dpp(0, __builtin_bit_cast(int, x), 0x124, 0xF, 0xF, false);
  x += __builtin_bit_cast(float, t);
  t = __builtin_amdgcn_update_dpp(0, __builtin_bit_cast(int, x), 0x128, 0xF, 0xF, false);
  x += __builtin_bit_cast(float, t);
  return x;
}

// ---- contention-free 2-level slot barrier (r8-proven, full 256 WGs) ----
__device__ __forceinline__ void gbar(unsigned* sb, unsigned& lg) {
  const unsigned tgt = lg + 1u;
  asm volatile("s_waitcnt vmcnt(0)" ::: "memory");
  __syncthreads();
  const int wg = (int)blockIdx.x;
  if (threadIdx.x < 64) {
    const int lane = (int)threadIdx.x;
    if (lane == 0)
      __hip_atomic_store(&sb[wg * 16], tgt, __ATOMIC_RELAXED, AGT);
    const int g = wg >> 5;
    if ((wg & 31) == 0) {                       // group leader
      if (lane < 32) {
        const unsigned* slot = &sb[(g * 32 + lane) * 16];
        while (__hip_atomic_load(slot, __ATOMIC_RELAXED, AGT) < tgt)
          __builtin_amdgcn_s_sleep(1);
      }
      if (lane == 0)
        __hip_atomic_store(&sb[4096 + g * 16], tgt, __ATOMIC_RELAXED, AGT);
    }
    if (lane < 8) {
      const unsigned* f = &sb[4096 + lane * 16];
      while (__hip_atomic_load(f, __ATOMIC_RELAXED, AGT) < tgt)
        __builtin_amdgcn_s_sleep(1);
    }
  }
  lg = tgt;
  __syncthreads();
}

__device__ __forceinline__ float blockMax(float v, float* red, int tid) {
#pragma unroll
  for (int off = 32; off > 0; off >>= 1) v = fmaxf(v, __shfl_xor(v, off, 64));
  if ((tid & 63) == 0) red[tid >> 6] = v;
  __syncthreads();
  float m = red[0];
#pragma unroll
  for (int i = 1; i < 8; ++i) m = fmaxf(m, red[i]);
  __syncthreads();
  return m;
}

__device__ __forceinline__ float blockSum(float v, float* red, int tid) {
  v = wredsum(v);
  if ((tid & 63) == 0) red[tid >> 6] = v;
  __syncthreads();
  float s = 0.f;
#pragma unroll
  for (int i = 0; i < 8; ++i) s += red[i];
  __syncthreads();
  return s;
}

// ---- stage 48 weight rows (4 cols/WG), slant-packed: rr = m*16 + q*4 + dl ----
__device__ __forceinline__ void stageW4(int wg, int tid, const float* __restrict__ Wih,
                                        const float* __restrict__ Whh, float* __restrict__ SMW) {
  for (int e = tid; e < 48 * 512; e += TPB) {
    const int k = e & 511, rr = e >> 9;
    const int m = rr >> 4, q = (rr >> 2) & 3, dl = rr & 3;
    const int j = q * 512 + wg * 4 + dl;
    const float* srcp = (m == 0) ? (Whh + (size_t)j * 512)
                     : (m == 1) ? (Wih + (size_t)2048 * 512 + (size_t)j * 512)
                                : (Whh + (size_t)2048 * 512 + (size_t)j * 512);
    SMW[rr * 576 + (k >> 5) * 36 + (k & 31)] = srcp[k];
  }
  __syncthreads();
}

// ---- WG-private build of ETb[v/2][k][2] (panel [wg*128, +128)); sc1 stores ----
__device__ __forceinline__ void buildETb(int wg, int tid, const float* __restrict__ Etrg,
                                         float* __restrict__ ETb, float* __restrict__ SM) {
  if (wg < 250) {
    for (int tile = 0; tile < 8; ++tile) {
      const int tv = tile >> 2, tk = tile & 3;
      __syncthreads();
      for (int e = tid; e < 64 * 128; e += TPB) {
        const int vl = e >> 7, kl = e & 127;
        SM[vl * 129 + kl] = Etrg[(size_t)(wg * 128 + tv * 64 + vl) * 512 + tk * 128 + kl];
      }
      __syncthreads();
      for (int e = tid; e < 32 * 128; e += TPB) {
        const int vp = e >> 7, kl = e & 127;
        const int v = wg * 128 + tv * 64 + vp * 2;
        const int k = tk * 128 + kl;
        float2 val = make_float2(SM[(vp * 2) * 129 + kl], SM[(vp * 2 + 1) * 129 + kl]);
        stcv2(ETb + ((size_t)(v >> 1) * 512 + k) * 2, val);
      }
    }
    __syncthreads();
  }
}

// ---- phaseAB4 helpers: quarter-staged H (16 KB), vmcnt(0)-only waits ----
__device__ __forceinline__ void ld2q(const float* base, int tid, float4 s[2]) {
  const float* p0 = base + tid * 4;
  const float* p1 = base + 2048 + tid * 4;
  asm volatile("global_load_dwordx4 %0, %1, off sc1" : "=v"(s[0]) : "v"(p0));
  asm volatile("global_load_dwordx4 %0, %1, off sc1" : "=v"(s[1]) : "v"(p1));
}
__device__ __forceinline__ void stage2(char* LHc, int tid, const float4 s[2]) {
  int byA = tid * 16;         byA ^= ((byA >> 8) & 7) << 4;
  int byB = (512 + tid) * 16; byB ^= ((byB >> 8) & 7) << 4;
  *(float4*)(LHc + byA) = s[0];
  *(float4*)(LHc + byB) = s[1];
}
__device__ __forceinline__ void readHq4(const char* LHc, int b2l, int kc, float4 hq[16]) {
#pragma unroll
  for (int i = 0; i < 16; ++i) {
    int byte = b2l * 4096 + kc * 256 + i * 16;
    byte ^= ((byte >> 8) & 7) << 4;
    hq[i] = *(const float4*)(LHc + byte);
  }
}
// dot of slant-packed W row rr with paired H fragments -> float2 (b even, b odd)
__device__ __forceinline__ void dotMQ(const float* __restrict__ SMW, int rr, int kc,
                                      const float4* __restrict__ hq, float2& acc) {
  const float4* wr = (const float4*)(SMW + rr * 576 + kc * 36);
#pragma unroll
  for (int i2 = 0; i2 < 8; ++i2) {
    const float4 wv = wr[i2];
    const float4 hA = hq[i2 * 2], hB = hq[i2 * 2 + 1];
    acc.x = fmaf(wv.x, hA.x, acc.x); acc.y = fmaf(wv.x, hA.y, acc.y);
    acc.x = fmaf(wv.y, hA.z, acc.x); acc.y = fmaf(wv.y, hA.w, acc.y);
    acc.x = fmaf(wv.z, hB.x, acc.x); acc.y = fmaf(wv.z, hB.y, acc.y);
    acc.x = fmaf(wv.w, hB.z, acc.x); acc.y = fmaf(wv.w, hB.w, acc.y);
  }
}

// ---- merged LSTM phase, 4 cols/WG (WGs 0..127). tid = b2*32 + dh*16 + kc. ----
__device__ __forceinline__ void phaseAB4(
    int wg, int tid, bool doA, bool doB,
    const float* __restrict__ H0r, float* __restrict__ H0w,
    const float* __restrict__ H1r, float* __restrict__ H1w,
    float* __restrict__ HlP, const float* __restrict__ Pp,
    const float bs1v[2][4], const float* __restrict__ SMW, float* __restrict__ LH,
    float c0[2][2], float c1[2][2])
{
  const int b2 = tid >> 5, dh = (tid >> 4) & 1, kc = tid & 15;
  const int q4 = b2 >> 2, b2l = b2 & 3;
  char* LHc = (char*)LH;
  float4 s[2], hq[16];

  // ---- H0: 4 quarter-rounds (16 KB each), vmcnt(0)-only ----
  ld2q(H0r, tid, s);
#pragma unroll
  for (int qq = 0; qq < 4; ++qq) {
    asm volatile("s_waitcnt vmcnt(0)" ::: "memory");
    __builtin_amdgcn_sched_barrier(0);
    stage2(LHc, tid, s);
    if (qq < 3) ld2q(H0r + (qq + 1) * 4096, tid, s);
    else if (doB) ld2q(H1r, tid, s);         // first H1 quarter flies under dots
    __syncthreads();
    if (q4 == qq) readHq4(LHc, b2l, kc, hq);
    __syncthreads();
  }

  float2 a2[2][12];
#pragma unroll
  for (int dlx = 0; dlx < 2; ++dlx)
#pragma unroll
    for (int j = 0; j < 12; ++j) a2[dlx][j] = make_float2(0.f, 0.f);

  if (doA) {
#pragma unroll
    for (int dlx = 0; dlx < 2; ++dlx)
#pragma unroll
      for (int q = 0; q < 4; ++q)
        dotMQ(SMW, q * 4 + dh * 2 + dlx, kc, hq, a2[dlx][q]);          // Whh0.H0
  }
  if (doB) {
#pragma unroll
    for (int dlx = 0; dlx < 2; ++dlx)
#pragma unroll
      for (int q = 0; q < 4; ++q)
        dotMQ(SMW, 16 + q * 4 + dh * 2 + dlx, kc, hq, a2[dlx][4 + q]); // Wih1.H0
    // ---- H1: 4 quarter-rounds ----
#pragma unroll
    for (int qq = 0; qq < 4; ++qq) {
      asm volatile("s_waitcnt vmcnt(0)" ::: "memory");
      __builtin_amdgcn_sched_barrier(0);
      stage2(LHc, tid, s);
      if (qq < 3) ld2q(H1r + (qq + 1) * 4096, tid, s);
      __syncthreads();
      if (q4 == qq) readHq4(LHc, b2l, kc, hq);
      __syncthreads();
    }
#pragma unroll
    for (int dlx = 0; dlx < 2; ++dlx)
#pragma unroll
      for (int q = 0; q < 4; ++q)
        dotMQ(SMW, 32 + q * 4 + dh * 2 + dlx, kc, hq, a2[dlx][8 + q]); // Whh1.H1
  }

#pragma unroll
  for (int dlx = 0; dlx < 2; ++dlx)
#pragma unroll
    for (int j = 0; j < 12; ++j) {
      if (j < 4 ? !doA : !doB) continue;
      a2[dlx][j].x = rowReduce16(a2[dlx][j].x);
      a2[dlx][j].y = rowReduce16(a2[dlx][j].y);
    }

  if (kc == 0) {                      // 32 lanes own (b2, dh); 2 cols each
#pragma unroll
    for (int dlx = 0; dlx < 2; ++dlx) {
      const int d = (wg << 2) | (dh << 1) | dlx;
      if (doA) {
#pragma unroll
        for (int p = 0; p < 2; ++p) {
          const int b = b2 * 2 + p;
          const float* pb = Pp + b * 2048 + d;
          const float gi = (p ? a2[dlx][0].y : a2[dlx][0].x) + pb[0];
          const float gf = (p ? a2[dlx][1].y : a2[dlx][1].x) + pb[512];
          const float gg = (p ? a2[dlx][2].y : a2[dlx][2].x) + pb[1024];
          const float go = (p ? a2[dlx][3].y : a2[dlx][3].x) + pb[1536];
          c0[dlx][p] = sigm(gf) * c0[dlx][p] + sigm(gi) * tanhf(gg);
          stcv(H0w + b2 * 1024 + d * 2 + p, sigm(go) * tanhf(c0[dlx][p]));
        }
      }
      if (doB) {
#pragma unroll
        for (int p = 0; p < 2; ++p) {
          const float gi = (p ? a2[dlx][4].y : a2[dlx][4].x) + (p ? a2[dlx][8].y  : a2[dlx][8].x)  + bs1v[dlx][0];
          const float gf = (p ? a2[dlx][5].y : a2[dlx][5].x) + (p ? a2[dlx][9].y  : a2[dlx][9].x)  + bs1v[dlx][1];
          const float gg = (p ? a2[dlx][6].y : a2[dlx][6].x) + (p ? a2[dlx][10].y : a2[dlx][10].x) + bs1v[dlx][2];
          const float go = (p ? a2[dlx][7].y : a2[dlx][7].x) + (p ? a2[dlx][11].y : a2[dlx][11].x) + bs1v[dlx][3];
          c1[dlx][p] = sigm(gf) * c1[dlx][p] + sigm(gi) * tanhf(gg);
          const float hn = sigm(go) * tanhf(c1[dlx][p]);
          stcv(H1w + b2 * 1024 + d * 2 + p, hn);
          if (HlP) stcv(HlP + b2 * 1024 + d * 2 + p, hn);
        }
      }
    }
  }
}

// ---- fused fc + attention + context + h2o for one batch row (WGs 0..31) ----
__device__ __forceinline__ void phaseCDEF(int b, int tid, const float* __restrict__ H1c,
                          const float* __restrict__ Wfc, const float* __restrict__ bfc,
                          const int* __restrict__ src, const float* __restrict__ Esrc,
                          const float* __restrict__ Wh2o, const float* __restrict__ bh2o,
                          float* __restrict__ hD, float* sc, float* rb, int* ib, float* red)
{
  rb[tid] = ldcv(H1c + (b >> 1) * 1024 + tid * 2 + (b & 1));  // paired layout
  ib[tid] = src[b * 512 + tid];
  __syncthreads();
  const int w = tid >> 6, lane = tid & 63;
  for (int d = w; d < 512; d += 8) {            // fc_out
    const float* wr = Wfc + (size_t)d * 512;
    float p = 0.f;
#pragma unroll
    for (int i = 0; i < 8; ++i) p = fmaf(rb[lane * 8 + i], wr[lane * 8 + i], p);
    p = wredsum(p);
    if (lane == 0) rb[512 + d] = p + bfc[d];
  }
  __syncthreads();
  for (int s = w; s < 512; s += 8) {            // scores
    const float* er = Esrc + (size_t)ib[s] * 512;
    float p = 0.f;
#pragma unroll
    for (int i = 0; i < 8; ++i) p = fmaf(rb[512 + lane * 8 + i], er[lane * 8 + i], p);
    p = wredsum(p);
    if (lane == 0) sc[s] = p * SCALE_INV;
  }
  __syncthreads();
  const float mx = blockMax(sc[tid], red, tid);
  const float e = expf(sc[tid] - mx);
  sc[tid] = e;
  const float sum = blockSum(e, red, tid);
  const float inv = 1.0f / sum;
  float acc = 0.f;
#pragma unroll 4
  for (int s = 0; s < 512; ++s) acc = fmaf(sc[s], Esrc[(size_t)ib[s] * 512 + tid], acc);
  rb[tid] = acc * inv;                          // ctx
  __syncthreads();
  for (int d = w; d < 512; d += 8) {            // h2o + relu
    const float* wr = Wh2o + (size_t)d * 1024;
    float p = 0.f;
#pragma unroll
    for (int i = 0; i < 8; ++i) p = fmaf(rb[512 + lane * 8 + i], wr[lane * 8 + i], p);
#pragma unroll
    for (int i = 0; i < 8; ++i) p = fmaf(rb[lane * 8 + i], wr[512 + lane * 8 + i], p);
    p = wredsum(p);
    if (lane == 0) stcv(hD + (size_t)b * 512 + d, fmaxf(p + bh2o[d], 0.f));
  }
  __syncthreads();
}

// ---- logits panel chunk: 256 v per G WG, k-half per chunk, all 32 b.
// Accumulator is LOCAL (registers); cross-chunk carry goes through the
// explicit LDS slab accL[idx*520 + tid] (conflict-free, no scratch).
__device__ __forceinline__ void phaseG_panelC(int wgG, int tid, int chunk,
                              const float* __restrict__ hD, const float* __restrict__ ETb,
                              const float* __restrict__ bout, float* __restrict__ candV,
                              int* __restrict__ candI, float* __restrict__ hblk,
                              float* __restrict__ gv, int* __restrict__ gi,
                              float* __restrict__ accL)
{
  if (wgG >= 125) return;
  float acc[4][4];
  if (chunk == 0) {
#pragma unroll
    for (int a = 0; a < 4; ++a)
#pragma unroll
      for (int b = 0; b < 4; ++b) acc[a][b] = 0.f;
  } else {
#pragma unroll
    for (int a = 0; a < 4; ++a)
#pragma unroll
      for (int b = 0; b < 4; ++b) acc[a][b] = accL[(a * 4 + b) * 520 + tid];
  }
  const int vp = tid >> 3, bh = tid & 7;
  const int v0 = wgG * 256 + vp * 4;
  const float* epA = ETb + (size_t)(v0 >> 1) * 1024 + chunk * 512;
  const float* epB = epA + 1024;
  const int fk = tid & 63, fb0 = tid >> 6;
  char* hb = (char*)hblk;

  for (int blk = 0; blk < 4; ++blk) {
    const int kb = chunk * 256 + blk * 64;
    __syncthreads();
#pragma unroll
    for (int i = 0; i < 4; ++i) {
      const int b = fb0 + i * 8;
      const float hv = ldcv(hD + (size_t)b * 512 + kb + fk);
      const int byte = fk * 128 + (((b >> 2) * 16) ^ ((fk & 7) << 4)) + ((b & 3) << 2);
      *(float*)(hb + byte) = hv;
    }
    __syncthreads();
#pragma unroll 8
    for (int kk = 0; kk < 64; kk += 2) {
      const float4 eA = *(const float4*)epA; epA += 4;
      const float4 eB = *(const float4*)epB; epB += 4;
      const float4 h0 = *(const float4*)(hb + kk * 128 + ((bh * 16) ^ ((kk & 7) << 4)));
      const float4 h1 = *(const float4*)(hb + (kk + 1) * 128 + ((bh * 16) ^ (((kk + 1) & 7) << 4)));
#pragma unroll
      for (int bj = 0; bj < 4; ++bj) {
        const float h0v = (bj == 0) ? h0.x : (bj == 1) ? h0.y : (bj == 2) ? h0.z : h0.w;
        const float h1v = (bj == 0) ? h1.x : (bj == 1) ? h1.y : (bj == 2) ? h1.z : h1.w;
        acc[0][bj] = fmaf(eA.x, h0v, acc[0][bj]);
        acc[0][bj] = fmaf(eA.z, h1v, acc[0][bj]);
        acc[1][bj] = fmaf(eA.y, h0v, acc[1][bj]);
        acc[1][bj] = fmaf(eA.w, h1v, acc[1][bj]);
        acc[2][bj] = fmaf(eB.x, h0v, acc[2][bj]);
        acc[2][bj] = fmaf(eB.z, h1v, acc[2][bj]);
        acc[3][bj] = fmaf(eB.y, h0v, acc[3][bj]);
        acc[3][bj] = fmaf(eB.w, h1v, acc[3][bj]);
      }
    }
  }
  if (chunk == 0) {
    __syncthreads();
#pragma unroll
    for (int a = 0; a < 4; ++a)
#pragma unroll
      for (int b = 0; b < 4; ++b) accL[(a * 4 + b) * 520 + tid] = acc[a][b];
    // no final syncthreads needed: same threads reload their own slots next chunk
  } else {
    const float bo[4] = {bout[v0], bout[v0 + 1], bout[v0 + 2], bout[v0 + 3]};
    const int w = tid >> 6;
#pragma unroll
    for (int bj = 0; bj < 4; ++bj) {
      float bv = acc[0][bj] + bo[0]; int bi = v0;
#pragma unroll
      for (int vj = 1; vj < 4; ++vj) {
        const float vv = acc[vj][bj] + bo[vj];
        if (vv > bv) { bv = vv; bi = v0 + vj; }
      }
#pragma unroll
      for (int off = 8; off < 64; off <<= 1) {
        const float ov = __shfl_xor(bv, off, 64); const int oi = __shfl_xor(bi, off, 64);
        if (ov > bv || (ov == bv && oi < bi)) { bv = ov; bi = oi; }
      }
      if ((tid & 63) < 8) {
        gv[(bh * 4 + bj) * 8 + w] = bv;
        gi[(bh * 4 + bj) * 8 + w] = bi;
      }
    }
    __syncthreads();
    if (tid < 32) {
      float bv = -INFINITY; int bi = 0;
      for (int w2 = 0; w2 < 8; ++w2) {
        const float vv = gv[tid * 8 + w2]; const int ii = gi[tid * 8 + w2];
        if (vv > bv || (vv == bv && ii < bi)) { bv = vv; bi = ii; }
      }
      stcv(candV + (size_t)tid * 256 + wgG, bv);
      stcvi(candI + tid * 256 + wgG, bi);
    }
    __syncthreads();
  }
}

// ---- fallback logits (row-major Etrg): 250 v per G WG, 32 b sequential ----
__device__ __forceinline__ void phaseG_noET2(int wgG, int tid, const float* __restrict__ hD,
                             const float* __restrict__ Etrg, const float* __restrict__ bout,
                             float* __restrict__ candV, int* __restrict__ candI,
                             float* rb, float* gv, int* gi)
{
  const int w = tid >> 6, lane = tid & 63;
  for (int b = 0; b < 32; ++b) {
    __syncthreads();
    rb[tid & 511] = ldcv(hD + (size_t)b * 512 + (tid & 511));
    __syncthreads();
    float bv = -INFINITY; int bi = 0x7fffffff;
    for (int v = wgG * 250 + w; v < wgG * 250 + 250; v += 8) {
      const float* er = Etrg + (size_t)v * 512;
      float p = 0.f;
#pragma unroll
      for (int i = 0; i < 8; ++i) p = fmaf(rb[lane * 8 + i], er[lane * 8 + i], p);
      p = wredsum(p);
      p += bout[v];
      if (p > bv || (p == bv && v < bi)) { bv = p; bi = v; }
    }
    if (lane == 0) { gv[w] = bv; gi[w] = bi; }
    __syncthreads();
    if (tid == 0) {
      float fv = -INFINITY; int fi = 0x7fffffff;
      for (int w2 = 0; w2 < 8; ++w2)
        if (gv[w2] > fv || (gv[w2] == fv && gi[w2] < fi)) { fv = gv[w2]; fi = gi[w2]; }
      stcv(candV + (size_t)b * 256 + wgG, fv);
      stcvi(candI + b * 256 + wgG, fi);
    }
  }
  __syncthreads();
}

// ---- token argmax finalize + this G WG's 16 rows of P[t+1] ----
__device__ __forceinline__ void phaseHP_G(int wgG, int tid, int t, int nslot,
                          const float* __restrict__ candV, const int* __restrict__ candI,
                          const float* __restrict__ Etrg, const float* __restrict__ Wih,
                          const float* __restrict__ bih, const float* __restrict__ bhh,
                          float* __restrict__ P, float* __restrict__ out, int* tokL)
{
  {
    const int b = tid >> 4, sl = tid & 15;
    float bv = -INFINITY; int bi = 0x7fffffff;
    for (int s = sl; s < nslot; s += 16) {
      const float vv = ldcv(candV + (size_t)b * 256 + s);
      const int ii = ldcvi(candI + b * 256 + s);
      if (vv > bv || (vv == bv && ii < bi)) { bv = vv; bi = ii; }
    }
#pragma unroll
    for (int off = 1; off < 16; off <<= 1) {
      const float ov = __shfl_xor(bv, off, 64); const int oi = __shfl_xor(bi, off, 64);
      if (ov > bv || (ov == bv && oi < bi)) { bv = ov; bi = oi; }
    }
    if (sl == 0) {
      tokL[b] = bi;
      if (wgG == 0) stcv(out + b * 32 + t, (float)bi);   // tokens[:,1:][b][t]
    }
  }
  __syncthreads();
  if (t < 31) {
    const int w = tid >> 6, lane = tid & 63;
    for (int jj = w; jj < 16; jj += 8) {
      const int j = wgG * 16 + jj;
      const float* wr = Wih + (size_t)j * 512;
      const float bsum = bih[j] + bhh[j];
      for (int b = 0; b < 32; ++b) {
        const float* er = Etrg + (size_t)tokL[b] * 512;
        float p = 0.f;
#pragma unroll
        for (int i = 0; i < 8; ++i) p = fmaf(er[lane * 8 + i], wr[lane * 8 + i], p);
        p = wredsum(p);
        if (lane == 0) stcv(P + ((size_t)(t + 1) * 32 + b) * 2048 + j, p + bsum);
      }
    }
  }
  __syncthreads();
}

// ---- outfc[p][b][:] = Hlast[p][b] @ Wfc^T + bfc (paired Hl; 1 unit/WG) ----
__device__ __forceinline__ void phaseX(int wg, int tid, const float* __restrict__ Hl,
                       const float* __restrict__ Wfc,
                       const float* __restrict__ bfc, float* __restrict__ oF)
{
  const int p = wg >> 3, bq = wg & 7;
  const int w = tid >> 6, lane = tid & 63;
  for (int u = w; u < 1024; u += 8) {
    const int b2 = bq * 2 + (u >> 9), d = u & 511;
    const float* hr = Hl + (size_t)p * BD + b2 * 1024;
    const float* wr = Wfc + (size_t)d * 512;
    float ax = 0.f, ay = 0.f;
#pragma unroll
    for (int i = 0; i < 8; ++i) {
      const float2 hv = ldcv2(hr + (lane * 8 + i) * 2);
      const float wv = wr[lane * 8 + i];
      ax = fmaf(hv.x, wv, ax);
      ay = fmaf(hv.y, wv, ay);
    }
    ax = wredsum(ax); ay = wredsum(ay);
    if (lane == 0) {
      stcv(oF + ((size_t)p * 32 + b2 * 2    ) * 512 + d, ax + bfc[d]);
      stcv(oF + ((size_t)p * 32 + b2 * 2 + 1) * 512 + d, ay + bfc[d]);
    }
  }
}

// ---- final attn rows: 4 per WG ----
__device__ __forceinline__ void phaseY(int wg, int tid, const float* __restrict__ oF,
                       const int* __restrict__ src,
                       const float* __restrict__ Esrc, float* __restrict__ out,
                       float* sc, float* rb, int* ib, float* red)
{
  for (int r = 0; r < 4; ++r) {
    const int id = wg * 4 + r;
    const int b = id >> 5, p = id & 31;
    __syncthreads();
    rb[tid] = ldcv(oF + ((size_t)p * 32 + b) * 512 + tid);
    ib[tid] = src[b * 512 + tid];
    __syncthreads();
    const int w = tid >> 6, lane = tid & 63;
    for (int s = w; s < 512; s += 8) {
      const float* er = Esrc + (size_t)ib[s] * 512;
      float acc = 0.f;
#pragma unroll
      for (int i = 0; i < 8; ++i) acc = fmaf(rb[lane * 8 + i], er[lane * 8 + i], acc);
      acc = wredsum(acc);
      if (lane == 0) sc[s] = acc * SCALE_INV;
    }
    __syncthreads();
    const float mx = blockMax(sc[tid], red, tid);
    const float e = expf(sc[tid] - mx);
    const float sum = blockSum(e, red, tid);
    out[1024 + ((size_t)b * 32 + p) * 512 + tid] = e / sum;
  }
}

extern "C" __global__ void __launch_bounds__(TPB)
s2s_mega(const int* __restrict__ src, const float* __restrict__ Esrc, const float* __restrict__ Etrg,
         const float* __restrict__ Wih, const float* __restrict__ Whh,
         const float* __restrict__ bih, const float* __restrict__ bhh,
         const float* __restrict__ Wfc, const float* __restrict__ bfc,
         const float* __restrict__ Wh2o, const float* __restrict__ bh2o,
         const float* __restrict__ bout, float* __restrict__ out,
         float* __restrict__ ws, const float* __restrict__ ET, float* __restrict__ ETw)
{
  extern __shared__ float SM[];
  float* SMW = SM + L_W;
  float* LH  = SM + L_H;
  // overlays
  float* hblk = SM + G_HB;
  float* gv  = SM + G_GV;
  int*   gi  = (int*)(SM + G_GI);
  int*   tokG = (int*)(SM + G_TOK);
  float* accL = SM + G_ACC;
  float* scY = SM + S_SC;
  float* rbY = SM + S_RB;
  int*   ibY = (int*)(SM + S_IB);
  float* redY = SM + S_RED;

  unsigned* sb = (unsigned*)ws;
  float* H0 = ws + OFF_H0;
  float* H1 = ws + OFF_H1;
  float* P  = ws + OFF_P;
  float* Hl = ws + OFF_HL;
  float* hD = ws + OFF_HD;
  float* oF = ws + OFF_OF;
  float* cV = ws + OFF_CV;
  int*   cI = (int*)(ws + OFF_CI);

  const int wg = blockIdx.x, tid = threadIdx.x;
  const bool useET = (ET != nullptr);
  unsigned lg = 0u;
  float c0[2][2] = {{0.f, 0.f}, {0.f, 0.f}};
  float c1[2][2] = {{0.f, 0.f}, {0.f, 0.f}};
  float bs1v[2][4] = {{0.f,0.f,0.f,0.f},{0.f,0.f,0.f,0.f}};

  if (wg < 128) {       // layer-1 bias sums for this WG's 4 columns
    const int dh = (tid >> 4) & 1;
#pragma unroll
    for (int dlx = 0; dlx < 2; ++dlx) {
      const int d = (wg << 2) | (dh << 1) | dlx;
#pragma unroll
      for (int q = 0; q < 4; ++q)
        bs1v[dlx][q] = bih[2048 + q * 512 + d] + bhh[2048 + q * 512 + d];
    }
  }

  // ---- setup: zero carried H state ----
  {
    const int gid = wg * TPB + tid;
    if (gid < BD) stcv(H0 + gid, 0.f);
    else if (gid < 2 * BD) stcv(H1 + gid - BD, 0.f);
  }
  // ---- P[0] = emb([SOS]) @ Wih0^T + biases (all 256 WGs, 8 rows each) ----
  {
    const int w = tid >> 6, lane = tid & 63;
    const int q = w >> 1, dl = w & 1;
    const int j = q * 512 + wg * 2 + dl;
    const float* er = Etrg + 512;               // token 1 ([SOS])
    const float* wr = Wih + (size_t)j * 512;
    float p = 0.f;
#pragma unroll
    for (int i = 0; i < 8; ++i) p = fmaf(er[lane * 8 + i], wr[lane * 8 + i], p);
    p = wredsum(p);
    p += bih[j] + bhh[j];
    if (lane < 32) stcv(P + (size_t)lane * 2048 + j, p);
  }
  if (ETw) buildETb(wg, tid, Etrg, ETw, SM);
  if (wg < 128) stageW4(wg, tid, Wih, Whh, SMW);
  gbar(sb, lg);

  int cur0 = 0, cur1 = 0;
  for (int t = 0; t < 32; ++t) {
    for (int k = 0; k <= t + 1; ++k) {
      const bool doA = (k <= t), doB = (k >= 1);
      if (wg < 128) {
        float* HlP = (t == 31 && doB) ? (Hl + (size_t)(k - 1) * BD) : nullptr;
        const int kp = (k < 32) ? k : 31;
        phaseAB4(wg, tid, doA, doB,
                 H0 + (size_t)cur0 * BD, H0 + (size_t)(cur0 ^ 1) * BD,
                 H1 + (size_t)cur1 * BD, H1 + (size_t)(cur1 ^ 1) * BD,
                 HlP, P + (size_t)kp * Bb * 2048, bs1v, SMW, LH, c0, c1);
      } else {
        const int wgG = wg - 128;
        if (useET) {
          if (t >= 2 && k == 0) {
            phaseG_panelC(wgG, tid, 0, hD, ET, bout, cV, cI, hblk, gv, gi, accL);
            if (t == 2) phaseG_panelC(wgG, tid, 1, hD, ET, bout, cV, cI, hblk, gv, gi, accL);
          }
          if (t >= 3 && k == 1)
            phaseG_panelC(wgG, tid, 1, hD, ET, bout, cV, cI, hblk, gv, gi, accL);
          if (t == 2 && k == 1)
            phaseHP_G(wgG, tid, 1, 125, cV, cI, Etrg, Wih, bih, bhh, P, out, tokG);
          if (t >= 3 && k == 2)
            phaseHP_G(wgG, tid, t - 1, 125, cV, cI, Etrg, Wih, bih, bhh, P, out, tokG);
        } else {
          if (t >= 2 && k == 0)
            phaseG_noET2(wgG, tid, hD, Etrg, bout, cV, cI, hblk, gv, gi);
          if (t == 2 && k == 1)
            phaseHP_G(wgG, tid, 1, 128, cV, cI, Etrg, Wih, bih, bhh, P, out, tokG);
          if (t >= 3 && k == 2)
            phaseHP_G(wgG, tid, t - 1, 128, cV, cI, Etrg, Wih, bih, bhh, P, out, tokG);
        }
      }
      gbar(sb, lg);
      if (doA) cur0 ^= 1;
      if (doB) cur1 ^= 1;
    }
    if (wg < 32) phaseCDEF(wg, tid, H1 + (size_t)cur1 * BD, Wfc, bfc, src, Esrc,
                           Wh2o, bh2o, hD, scY, rbY, ibY, redY);
    gbar(sb, lg);
    if (t == 0) {       // bootstrap: G(0) + HP(0) standalone
      if (wg >= 128) {
        const int wgG = wg - 128;
        if (useET) {
          phaseG_panelC(wgG, tid, 0, hD, ET, bout, cV, cI, hblk, gv, gi, accL);
          phaseG_panelC(wgG, tid, 1, hD, ET, bout, cV, cI, hblk, gv, gi, accL);
        } else {
          phaseG_noET2(wgG, tid, hD, Etrg, bout, cV, cI, hblk, gv, gi);
        }
      }
      gbar(sb, lg);
      if (wg >= 128)
        phaseHP_G(wg - 128, tid, 0, useET ? 125 : 128, cV, cI, Etrg, Wih, bih, bhh, P, out, tokG);
      gbar(sb, lg);
    }
  }
  // ---- tail: X + G(31); then HP(31) token finalize + Y ----
  phaseX(wg, tid, Hl, Wfc, bfc, oF);
  if (wg >= 128) {
    const int wgG = wg - 128;
    if (useET) {
      phaseG_panelC(wgG, tid, 0, hD, ET, bout, cV, cI, hblk, gv, gi, accL);
      phaseG_panelC(wgG, tid, 1, hD, ET, bout, cV, cI, hblk, gv, gi, accL);
    } else {
      phaseG_noET2(wgG, tid, hD, Etrg, bout, cV, cI, hblk, gv, gi);
    }
  }
  gbar(sb, lg);
  if (wg >= 128)
    phaseHP_G(wg - 128, tid, 31, useET ? 125 : 128, cV, cI, Etrg, Wih, bih, bhh, P, out, tokG);
  phaseY(wg, tid, oF, src, Esrc, out, scY, rbY, ibY, redY);
}

extern "C" void kernel_launch(void* const* d_in, const int* in_sizes, int n_in,
                              void* d_out, int out_size, void* d_ws, size_t ws_size,
                              hipStream_t stream) {
  const int*   src  = (const int*)d_in[0];
  const float* Esrc = (const float*)d_in[1];
  const float* Etrg = (const float*)d_in[2];
  const float* Wih  = (const float*)d_in[3];
  const float* Whh  = (const float*)d_in[4];
  const float* bih  = (const float*)d_in[5];
  const float* bhh  = (const float*)d_in[6];
  const float* Wfc  = (const float*)d_in[7];
  const float* bfc  = (const float*)d_in[8];
  const float* Wh2o = (const float*)d_in[9];
  const float* bh2o = (const float*)d_in[10];
  const float* bout = (const float*)d_in[11];
  float* ws = (float*)d_ws;

  const size_t needET = (OFF_ET + (size_t)512 * 32000) * sizeof(float);
  const bool useET = (ws_size >= needET);
  float* etw = useET ? (ws + OFF_ET) : nullptr;

  (void)hipMemsetAsync(d_ws, 0, 32768, stream);   // reset barrier slots + flags

  (void)hipFuncSetAttribute(reinterpret_cast<const void*>(&s2s_mega),
                            hipFuncAttributeMaxDynamicSharedMemorySize, (int)LDS_BYTES);

  s2s_mega<<<dim3(NWG), dim3(TPB), LDS_BYTES, stream>>>(
      src, Esrc, Etrg, Wih, Whh, bih, bhh, Wfc, bfc, Wh2o, bh2o, bout,
      (float*)d_out, ws, etw, etw);
}

// Round 14
// 18086.716 us; speedup vs baseline: 2.6421x; 2.5683x over previous
//
#include <hip/hip_runtime.h>
#include <math.h>

#define NWG 256
#define TPB 512
#define AGT __HIP_MEMORY_SCOPE_AGENT

// ---- sizes ----
static constexpr int Bb = 32, Dd = 512, Tt = 32, Vv = 32000;
static constexpr int BD = Bb * Dd;                       // 16384
static constexpr float SCALE_INV = 0.04419417382415922f; // 1/sqrt(512)

// ---- ws layout (float offsets). Sync region = first 32 KB. ----
// H0/H1/Hl use PAIRED layout: element (b,k) at [b>>1]*1024 + k*2 + (b&1).
static constexpr size_t OFF_H0 = 8192;
static constexpr size_t OFF_H1 = OFF_H0 + 2 * (size_t)BD;
static constexpr size_t OFF_P  = OFF_H1 + 2 * (size_t)BD;             // [32][32][2048]
static constexpr size_t OFF_HL = OFF_P + (size_t)Tt * Bb * 2048;      // [32] paired blocks
static constexpr size_t OFF_HD = OFF_HL + (size_t)Tt * BD;
static constexpr size_t OFF_OF = OFF_HD + BD;                          // [32][32][512]
static constexpr size_t OFF_CV = OFF_OF + (size_t)Tt * BD;             // [32][256]
static constexpr size_t OFF_CI = OFF_CV + 32 * 256;
static constexpr size_t OFF_ET = OFF_CI + 32 * 256;                    // ETb [16000][512][2]

// ---- LDS region offsets (floats) ----
static constexpr int L_W   = 0;       // 24 x 576 slant-packed weight rows = 13824
static constexpr int L_ST  = 13824;   // 16384: AB H-stage / ETb-build tile / CDEF+Y scratch
static constexpr int L_SC  = 13824;   //   sc  (512)  [CDEF/Y phases only]
static constexpr int L_RB  = 14336;   //   rb  (1024)
static constexpr int L_IB  = 15360;   //   ib  (512)
static constexpr int L_RED = 15872;   //   red (16)
static constexpr int L_HB  = 30208;   // 2048: G hidT block [64k][32b] swizzled
static constexpr int L_GV  = 32256;   // 256
static constexpr int L_GI  = 32512;   // 256
static constexpr int L_TOK = 32768;   // 32
static constexpr int LDS_FLOATS = 32800;
static constexpr size_t LDS_BYTES = (size_t)LDS_FLOATS * 4;   // 131200

__device__ __forceinline__ float sigm(float x) { return 1.0f / (1.0f + expf(-x)); }

// ---- IC-coherent (sc1) access: relaxed agent-scope atomics ----
__device__ __forceinline__ float ldcv(const float* p) {
  unsigned u = __hip_atomic_load((const unsigned*)p, __ATOMIC_RELAXED, AGT);
  return __builtin_bit_cast(float, u);
}
__device__ __forceinline__ void stcv(float* p, float v) {
  __hip_atomic_store((unsigned*)p, __builtin_bit_cast(unsigned, v), __ATOMIC_RELAXED, AGT);
}
__device__ __forceinline__ float2 ldcv2(const float* p) {
  unsigned long long u = __hip_atomic_load((const unsigned long long*)p, __ATOMIC_RELAXED, AGT);
  return __builtin_bit_cast(float2, u);
}
__device__ __forceinline__ void stcv2(float* p, float2 v) {
  __hip_atomic_store((unsigned long long*)p, __builtin_bit_cast(unsigned long long, v),
                     __ATOMIC_RELAXED, AGT);
}
__device__ __forceinline__ int ldcvi(const int* p) {
  return (int)__hip_atomic_load((const unsigned*)p, __ATOMIC_RELAXED, AGT);
}
__device__ __forceinline__ void stcvi(int* p, int v) {
  __hip_atomic_store((unsigned*)p, (unsigned)v, __ATOMIC_RELAXED, AGT);
}

__device__ __forceinline__ float wredsum(float v) {
#pragma unroll
  for (int off = 32; off > 0; off >>= 1) v += __shfl_xor(v, off, 64);
  return v;
}

// DPP rotate-reduce within each 16-lane row (pure VALU, no LDS pipe).
__device__ __forceinline__ float rowReduce16(float x) {
  int t;
  t = __builtin_amdgcn_update_dpp(0, __builtin_bit_cast(int, x), 0x121, 0xF, 0xF, false);
  x += __builtin_bit_cast(float, t);
  t = __builtin_amdgcn_update_dpp(0, __builtin_bit_cast(int, x), 0x122, 0xF, 0xF, false);
  x += __builtin_bit_cast(float, t);
  t = __builtin_amdgcn_update_dpp(0, __builtin_bit_cast(int, x), 0x124, 0xF, 0xF, false);
  x += __builtin_bit_cast(float, t);
  t = __builtin_amdgcn_update_dpp(0, __builtin_bit_cast(int, x), 0x128, 0xF, 0xF, false);
  x += __builtin_bit_cast(float, t);
  return x;
}

// H-stage LDS swizzle (identical on write & read; involution)
__device__ __forceinline__ int swzH(int byte) { return byte ^ (((byte >> 8) & 7) << 4); }

// ---- contention-free 2-level slot barrier ----
// WG wg stores generation to its own slot sb[wg*16] (64B apart).
// Group leader (wg%32==0) wave-gathers its 32 member slots, then sets group
// flag sb[4096+g*16]. Everyone polls the 8 group flags. No atomics RMW, no inv.
__device__ __forceinline__ void gbar(unsigned* sb, unsigned& lg) {
  const unsigned tgt = lg + 1u;
  asm volatile("s_waitcnt vmcnt(0)" ::: "memory");
  __syncthreads();
  const int wg = (int)blockIdx.x;
  if (threadIdx.x < 64) {
    const int lane = (int)threadIdx.x;
    if (lane == 0)
      __hip_atomic_store(&sb[wg * 16], tgt, __ATOMIC_RELAXED, AGT);
    const int g = wg >> 5;
    if ((wg & 31) == 0) {                       // group leader
      if (lane < 32) {
        const unsigned* slot = &sb[(g * 32 + lane) * 16];
        while (__hip_atomic_load(slot, __ATOMIC_RELAXED, AGT) < tgt)
          __builtin_amdgcn_s_sleep(1);
      }
      if (lane == 0)
        __hip_atomic_store(&sb[4096 + g * 16], tgt, __ATOMIC_RELAXED, AGT);
    }
    if (lane < 8) {
      const unsigned* f = &sb[4096 + lane * 16];
      while (__hip_atomic_load(f, __ATOMIC_RELAXED, AGT) < tgt)
        __builtin_amdgcn_s_sleep(1);
    }
  }
  lg = tgt;
  __syncthreads();
}

__device__ __forceinline__ float blockMax(float v, float* red, int tid) {
#pragma unroll
  for (int off = 32; off > 0; off >>= 1) v = fmaxf(v, __shfl_xor(v, off, 64));
  if ((tid & 63) == 0) red[tid >> 6] = v;
  __syncthreads();
  float m = red[0];
#pragma unroll
  for (int i = 1; i < 8; ++i) m = fmaxf(m, red[i]);
  __syncthreads();
  return m;
}

__device__ __forceinline__ float blockSum(float v, float* red, int tid) {
  v = wredsum(v);
  if ((tid & 63) == 0) red[tid >> 6] = v;
  __syncthreads();
  float s = 0.f;
#pragma unroll
  for (int i = 0; i < 8; ++i) s += red[i];
  __syncthreads();
  return s;
}

// ---- stage weights, slant-packed: row rr = m*8+q*2+dl, chunk kc at kc*36 ----
__device__ void stageW(int wg, int tid, const float* __restrict__ Wih,
                       const float* __restrict__ Whh, float* __restrict__ SMW) {
  for (int e = tid; e < 24 * 512; e += TPB) {
    const int k = e & 511, rr = e >> 9;
    const int m = rr >> 3, q = (rr >> 1) & 3, dl = rr & 1;
    const int j = q * 512 + wg * 2 + dl;
    const float* srcp = (m == 0) ? (Whh + (size_t)j * 512)
                     : (m == 1) ? (Wih + (size_t)2048 * 512 + (size_t)j * 512)
                                : (Whh + (size_t)2048 * 512 + (size_t)j * 512);
    SMW[rr * 576 + (k >> 5) * 36 + (k & 31)] = srcp[k];
  }
  __syncthreads();
}

// ---- WG-private build of ETb[v/2][k][2] from Etrg (panel [wg*128, +128)) ----
__device__ void buildETb(int wg, int tid, const float* __restrict__ Etrg,
                         float* __restrict__ ETb, float* __restrict__ SM) {
  if (wg < 250) {
    for (int tile = 0; tile < 8; ++tile) {
      const int tv = tile >> 2, tk = tile & 3;
      __syncthreads();
      for (int e = tid; e < 64 * 128; e += TPB) {
        const int vl = e >> 7, kl = e & 127;
        SM[vl * 129 + kl] = Etrg[(size_t)(wg * 128 + tv * 64 + vl) * 512 + tk * 128 + kl];
      }
      __syncthreads();
      for (int e = tid; e < 32 * 128; e += TPB) {
        const int vp = e >> 7, kl = e & 127;
        const int v = wg * 128 + tv * 64 + vp * 2;
        const int k = tk * 128 + kl;
        float2 val = make_float2(SM[(vp * 2) * 129 + kl], SM[(vp * 2 + 1) * 129 + kl]);
        stcv2(ETb + ((size_t)(v >> 1) * 512 + k) * 2, val);
      }
    }
    __syncthreads();
  }
}

// per-(m,q) dot: slant-packed W row rr x paired H fragments -> float2 (b0,b1)
__device__ __forceinline__ void dotMQ(const float* __restrict__ SMW, int rr, int kc,
                                      const float4* __restrict__ hq, float2& acc) {
  const float4* wr = (const float4*)(SMW + rr * 576 + kc * 36);
#pragma unroll
  for (int i2 = 0; i2 < 8; ++i2) {
    const float4 wv = wr[i2];
    const float4 hA = hq[i2 * 2], hB = hq[i2 * 2 + 1];
    acc.x = fmaf(wv.x, hA.x, acc.x); acc.y = fmaf(wv.x, hA.y, acc.y);
    acc.x = fmaf(wv.y, hA.z, acc.x); acc.y = fmaf(wv.y, hA.w, acc.y);
    acc.x = fmaf(wv.z, hB.x, acc.x); acc.y = fmaf(wv.z, hB.y, acc.y);
    acc.x = fmaf(wv.w, hB.z, acc.x); acc.y = fmaf(wv.w, hB.w, acc.y);
  }
}

// ---- merged LSTM phase: A = L0(pos p), B = L1(pos p-1). tid = b2*32 + dl*16 + kc ----
__device__ __forceinline__ void phaseAB(
    int wg, int tid, bool doA, bool doB,
    const float* __restrict__ H0r, float* __restrict__ H0w,
    const float* __restrict__ H1r, float* __restrict__ H1w,
    float* __restrict__ HlP, const float* __restrict__ Pp,
    const float* __restrict__ bs1v,
    const float* __restrict__ SMW, float* __restrict__ LH, float* c0, float* c1)
{
  const int b2 = tid >> 5, dl = (tid >> 4) & 1, kc = tid & 15;
  char* LHc = (char*)LH;
  float4 s0[8], s1[8];
  __builtin_amdgcn_sched_barrier(0);
  {
    const float* p0 = H0r + tid * 4;
#pragma unroll
    for (int r = 0; r < 8; ++r)
      asm volatile("global_load_dwordx4 %0, %1, off sc1" : "=v"(s0[r]) : "v"(p0 + r * 2048));
  }
  if (doB) {
    const float* p1 = H1r + tid * 4;
#pragma unroll
    for (int r = 0; r < 8; ++r)
      asm volatile("global_load_dwordx4 %0, %1, off sc1" : "=v"(s1[r]) : "v"(p1 + r * 2048));
    asm volatile("s_waitcnt vmcnt(8)" ::: "memory");   // s0 arrived
  } else {
    asm volatile("s_waitcnt vmcnt(0)" ::: "memory");
  }
  __builtin_amdgcn_sched_barrier(0);
#pragma unroll
  for (int r = 0; r < 8; ++r)
    *(float4*)(LHc + swzH((r * 512 + tid) * 16)) = s0[r];
  __syncthreads();
  float4 hq[16];
#pragma unroll
  for (int i = 0; i < 16; ++i)
    hq[i] = *(const float4*)(LHc + swzH(b2 * 4096 + kc * 256 + i * 16));

  float2 acc2[12];
#pragma unroll
  for (int j = 0; j < 12; ++j) acc2[j] = make_float2(0.f, 0.f);

  if (doA) {
#pragma unroll
    for (int q = 0; q < 4; ++q) dotMQ(SMW, q * 2 + dl, kc, hq, acc2[q]);        // Whh0.H0
  }
  if (doB) {
#pragma unroll
    for (int q = 0; q < 4; ++q) dotMQ(SMW, 8 + q * 2 + dl, kc, hq, acc2[4 + q]); // Wih1.H0
    asm volatile("s_waitcnt vmcnt(0)" ::: "memory");     // s1 arrived
    __builtin_amdgcn_sched_barrier(0);
    __syncthreads();                                     // all H0 reads done
#pragma unroll
    for (int r = 0; r < 8; ++r)
      *(float4*)(LHc + swzH((r * 512 + tid) * 16)) = s1[r];
    __syncthreads();
#pragma unroll
    for (int i = 0; i < 16; ++i)
      hq[i] = *(const float4*)(LHc + swzH(b2 * 4096 + kc * 256 + i * 16));
#pragma unroll
    for (int q = 0; q < 4; ++q) dotMQ(SMW, 16 + q * 2 + dl, kc, hq, acc2[8 + q]); // Whh1.H1
  }

#pragma unroll
  for (int j = 0; j < 12; ++j) {
    if (j < 4 ? !doA : !doB) continue;
    acc2[j].x = rowReduce16(acc2[j].x);
    acc2[j].y = rowReduce16(acc2[j].y);
  }

  if (kc == 0) {                       // 32 lanes/WG own (b2, dl); d = wg*2+dl
    const int d = (wg << 1) | dl;
    if (doA) {
#pragma unroll
      for (int p = 0; p < 2; ++p) {
        const int b = b2 * 2 + p;
        const float* pb = Pp + b * 2048 + d;
        const float gi = (p ? acc2[0].y : acc2[0].x) + pb[0];
        const float gf = (p ? acc2[1].y : acc2[1].x) + pb[512];
        const float gg = (p ? acc2[2].y : acc2[2].x) + pb[1024];
        const float go = (p ? acc2[3].y : acc2[3].x) + pb[1536];
        c0[p] = sigm(gf) * c0[p] + sigm(gi) * tanhf(gg);
        stcv(H0w + b2 * 1024 + d * 2 + p, sigm(go) * tanhf(c0[p]));
      }
    }
    if (doB) {
#pragma unroll
      for (int p = 0; p < 2; ++p) {
        const float gi = (p ? acc2[4].y : acc2[4].x) + (p ? acc2[8].y  : acc2[8].x)  + bs1v[0];
        const float gf = (p ? acc2[5].y : acc2[5].x) + (p ? acc2[9].y  : acc2[9].x)  + bs1v[1];
        const float gg = (p ? acc2[6].y : acc2[6].x) + (p ? acc2[10].y : acc2[10].x) + bs1v[2];
        const float go = (p ? acc2[7].y : acc2[7].x) + (p ? acc2[11].y : acc2[11].x) + bs1v[3];
        c1[p] = sigm(gf) * c1[p] + sigm(gi) * tanhf(gg);
        const float hn = sigm(go) * tanhf(c1[p]);
        stcv(H1w + b2 * 1024 + d * 2 + p, hn);
        if (HlP) stcv(HlP + b2 * 1024 + d * 2 + p, hn);
      }
    }
  }
}

// ---- fused fc + attention + context + h2o for one batch row (WGs 0..31) ----
__device__ void phaseCDEF(int b, int tid, const float* __restrict__ H1c,
                          const float* __restrict__ Wfc, const float* __restrict__ bfc,
                          const int* __restrict__ src, const float* __restrict__ Esrc,
                          const float* __restrict__ Wh2o, const float* __restrict__ bh2o,
                          float* __restrict__ hD, float* sc, float* rb, int* ib, float* red)
{
  rb[tid] = ldcv(H1c + (b >> 1) * 1024 + tid * 2 + (b & 1));  // paired layout
  ib[tid] = src[b * 512 + tid];
  __syncthreads();
  const int w = tid >> 6, lane = tid & 63;
  for (int d = w; d < 512; d += 8) {            // fc_out
    const float* wr = Wfc + (size_t)d * 512;
    float p = 0.f;
#pragma unroll
    for (int i = 0; i < 8; ++i) p = fmaf(rb[lane * 8 + i], wr[lane * 8 + i], p);
    p = wredsum(p);
    if (lane == 0) rb[512 + d] = p + bfc[d];
  }
  __syncthreads();
  for (int s = w; s < 512; s += 8) {            // scores
    const float* er = Esrc + (size_t)ib[s] * 512;
    float p = 0.f;
#pragma unroll
    for (int i = 0; i < 8; ++i) p = fmaf(rb[512 + lane * 8 + i], er[lane * 8 + i], p);
    p = wredsum(p);
    if (lane == 0) sc[s] = p * SCALE_INV;
  }
  __syncthreads();
  const float mx = blockMax(sc[tid], red, tid);
  const float e = expf(sc[tid] - mx);
  sc[tid] = e;
  const float sum = blockSum(e, red, tid);
  const float inv = 1.0f / sum;
  float acc = 0.f;
#pragma unroll 4
  for (int s = 0; s < 512; ++s) acc = fmaf(sc[s], Esrc[(size_t)ib[s] * 512 + tid], acc);
  rb[tid] = acc * inv;                          // ctx into rb[0:512]
  __syncthreads();
  for (int d = w; d < 512; d += 8) {            // h2o + relu
    const float* wr = Wh2o + (size_t)d * 1024;
    float p = 0.f;
#pragma unroll
    for (int i = 0; i < 8; ++i) p = fmaf(rb[512 + lane * 8 + i], wr[lane * 8 + i], p);
#pragma unroll
    for (int i = 0; i < 8; ++i) p = fmaf(rb[lane * 8 + i], wr[512 + lane * 8 + i], p);
    p = wredsum(p);
    if (lane == 0) stcv(hD + (size_t)b * 512 + d, fmaxf(p + bh2o[d], 0.f));
  }
}

// ---- single-pass logits chunk: k in [chunk*256, chunk*256+256), all 32 b.
// hblk[64][32] swizzled holds hidT for the current 64-k block (8 KB LDS).
// accG[8] = {v0:b0..3, v1:b0..3} persists in registers across chunks.
__device__ void phaseG(int wg, int tid, int chunk, float* __restrict__ accG,
                       const float* __restrict__ hD, const float* __restrict__ ETb,
                       const float* __restrict__ bout, float* __restrict__ candV,
                       int* __restrict__ candI, float* __restrict__ hblk,
                       float* __restrict__ gv, int* __restrict__ gi)
{
  if (wg >= 250) return;
  if (chunk == 0) {
#pragma unroll
    for (int j = 0; j < 8; ++j) accG[j] = 0.f;
  }
  const int vp = tid >> 3, bh = tid & 7;
  const int v = wg * 128 + vp * 2;
  const float* ep = ETb + (size_t)(v >> 1) * 1024 + chunk * 512;
  const int fk = tid & 63, fb0 = tid >> 6;
  char* hb = (char*)hblk;

  for (int blk = 0; blk < 4; ++blk) {
    const int kb = chunk * 256 + blk * 64;
    __syncthreads();
#pragma unroll
    for (int i = 0; i < 4; ++i) {               // fill hblk (coalesced hD read)
      const int b = fb0 + i * 8;
      const float hv = ldcv(hD + (size_t)b * 512 + kb + fk);
      const int byte = fk * 128 + (((b >> 2) * 16) ^ ((fk & 7) << 4)) + ((b & 3) << 2);
      *(float*)(hb + byte) = hv;
    }
    __syncthreads();
#pragma unroll 8
    for (int kk = 0; kk < 64; kk += 2) {
      const float4 e4 = *(const float4*)ep; ep += 4;   // (k,v0)(k,v1)(k+1,v0)(k+1,v1)
      const float4 ha = *(const float4*)(hb + kk * 128 + ((bh * 16) ^ ((kk & 7) << 4)));
      const float4 hbv = *(const float4*)(hb + (kk + 1) * 128 + ((bh * 16) ^ (((kk + 1) & 7) << 4)));
      accG[0] = fmaf(e4.x, ha.x, accG[0]);  accG[4] = fmaf(e4.y, ha.x, accG[4]);
      accG[1] = fmaf(e4.x, ha.y, accG[1]);  accG[5] = fmaf(e4.y, ha.y, accG[5]);
      accG[2] = fmaf(e4.x, ha.z, accG[2]);  accG[6] = fmaf(e4.y, ha.z, accG[6]);
      accG[3] = fmaf(e4.x, ha.w, accG[3]);  accG[7] = fmaf(e4.y, ha.w, accG[7]);
      accG[0] = fmaf(e4.z, hbv.x, accG[0]); accG[4] = fmaf(e4.w, hbv.x, accG[4]);
      accG[1] = fmaf(e4.z, hbv.y, accG[1]); accG[5] = fmaf(e4.w, hbv.y, accG[5]);
      accG[2] = fmaf(e4.z, hbv.z, accG[2]); accG[6] = fmaf(e4.w, hbv.z, accG[6]);
      accG[3] = fmaf(e4.z, hbv.w, accG[3]); accG[7] = fmaf(e4.w, hbv.w, accG[7]);
    }
  }

  if (chunk == 1) {                             // bout + argmax + write candidates
    const float bo0 = bout[v], bo1 = bout[v + 1];
    const int w = tid >> 6;
#pragma unroll
    for (int j = 0; j < 4; ++j) {
      const float va = accG[j] + bo0, vb = accG[4 + j] + bo1;
      float bv; int bi;
      if (vb > va) { bv = vb; bi = v + 1; } else { bv = va; bi = v; }
#pragma unroll
      for (int off = 8; off < 64; off <<= 1) {
        const float ov = __shfl_xor(bv, off, 64); const int oi = __shfl_xor(bi, off, 64);
        if (ov > bv || (ov == bv && oi < bi)) { bv = ov; bi = oi; }
      }
      if ((tid & 63) < 8) {
        gv[(bh * 4 + j) * 8 + w] = bv;
        gi[(bh * 4 + j) * 8 + w] = bi;
      }
    }
    __syncthreads();
    if (tid < 32) {
      float bv = -INFINITY; int bi = 0;
      for (int w2 = 0; w2 < 8; ++w2) {
        const float vv = gv[tid * 8 + w2]; const int ii = gi[tid * 8 + w2];
        if (vv > bv || (vv == bv && ii < bi)) { bv = vv; bi = ii; }
      }
      stcv(candV + (size_t)tid * 256 + wg, bv);
      stcvi(candI + tid * 256 + wg, bi);
    }
    __syncthreads();
  }
}

// ---- fallback logits (row-major E), wave-per-v ----
__device__ void phaseG_noET(int wg, int tid, const float* __restrict__ hD,
                            const float* __restrict__ Etrg, const float* __restrict__ bout,
                            float* __restrict__ candV, int* __restrict__ candI,
                            float* rb, float* gv, int* gi)
{
  const int b = wg >> 3, vb = wg & 7;
  rb[tid] = ldcv(hD + (size_t)b * 512 + tid);
  __syncthreads();
  const int w = tid >> 6, lane = tid & 63;
  float bv = -INFINITY; int bi = 0;
  for (int v = vb * 4000 + w; v < (vb + 1) * 4000; v += 8) {
    const float* er = Etrg + (size_t)v * 512;
    float p = 0.f;
#pragma unroll
    for (int i = 0; i < 8; ++i) p = fmaf(rb[lane * 8 + i], er[lane * 8 + i], p);
    p = wredsum(p);
    p += bout[v];
    if (p > bv || (p == bv && v < bi)) { bv = p; bi = v; }
  }
  if (lane == 0) { gv[w] = bv; gi[w] = bi; }
  __syncthreads();
  if (tid == 0) {
    float fv = -INFINITY; int fi = 0;
    for (int w2 = 0; w2 < 8; ++w2)
      if (gv[w2] > fv || (gv[w2] == fv && gi[w2] < fi)) { fv = gv[w2]; fi = gi[w2]; }
    stcv(candV + (size_t)b * 256 + vb, fv);
    stcvi(candI + b * 256 + vb, fi);
  }
  __syncthreads();
}

// ---- token argmax finalize + P[t+1] projection ----
__device__ void phaseHP(int wg, int tid, int t, bool useET,
                        const float* __restrict__ candV, const int* __restrict__ candI,
                        const float* __restrict__ Etrg, const float* __restrict__ Wih,
                        const float* __restrict__ bih, const float* __restrict__ bhh,
                        float* __restrict__ P, float* __restrict__ out, int* tokL)
{
  const int nslot = useET ? 250 : 8;
  {
    const int b = tid >> 4, sl = tid & 15;
    float bv = -INFINITY; int bi = 0x7fffffff;
    for (int s = sl; s < nslot; s += 16) {
      const float vv = ldcv(candV + (size_t)b * 256 + s);
      const int ii = ldcvi(candI + b * 256 + s);
      if (vv > bv || (vv == bv && ii < bi)) { bv = vv; bi = ii; }
    }
#pragma unroll
    for (int off = 1; off < 16; off <<= 1) {
      const float ov = __shfl_xor(bv, off, 64); const int oi = __shfl_xor(bi, off, 64);
      if (ov > bv || (ov == bv && oi < bi)) { bv = ov; bi = oi; }
    }
    if (sl == 0) {
      tokL[b] = bi;
      if (wg == 0) stcv(out + b * 32 + t, (float)bi);   // tokens[:,1:][b][t]
    }
  }
  __syncthreads();
  if (t < 31) {
    const int w = tid >> 6, lane = tid & 63;
    const int q = w >> 1, dl = w & 1;
    const int j = q * 512 + wg * 2 + dl;
    const float* wr = Wih + (size_t)j * 512;
    const float bsum = bih[j] + bhh[j];
    for (int b = 0; b < 32; ++b) {
      const float* er = Etrg + (size_t)tokL[b] * 512;
      float p = 0.f;
#pragma unroll
      for (int i = 0; i < 8; ++i) p = fmaf(er[lane * 8 + i], wr[lane * 8 + i], p);
      p = wredsum(p);
      if (lane == 0) stcv(P + ((size_t)(t + 1) * 32 + b) * 2048 + j, p + bsum);
    }
  }
  __syncthreads();
}

// ---- outfc[p][b][:] = Hlast[p][b] @ Wfc^T + bfc (paired Hl layout) ----
__device__ void phaseX(int wg, int tid, const float* __restrict__ Hl, const float* __restrict__ Wfc,
                       const float* __restrict__ bfc, float* __restrict__ oF)
{
  const int p = wg >> 3, bq = wg & 7;
  const int w = tid >> 6, lane = tid & 63;
  for (int u = w; u < 1024; u += 8) {
    const int b2 = bq * 2 + (u >> 9), d = u & 511;
    const float* hr = Hl + (size_t)p * BD + b2 * 1024;
    const float* wr = Wfc + (size_t)d * 512;
    float ax = 0.f, ay = 0.f;
#pragma unroll
    for (int i = 0; i < 8; ++i) {
      const float2 hv = ldcv2(hr + (lane * 8 + i) * 2);
      const float wv = wr[lane * 8 + i];
      ax = fmaf(hv.x, wv, ax);
      ay = fmaf(hv.y, wv, ay);
    }
    ax = wredsum(ax); ay = wredsum(ay);
    if (lane == 0) {
      stcv(oF + ((size_t)p * 32 + b2 * 2    ) * 512 + d, ax + bfc[d]);
      stcv(oF + ((size_t)p * 32 + b2 * 2 + 1) * 512 + d, ay + bfc[d]);
    }
  }
}

// ---- final attn rows ----
__device__ void phaseY(int wg, int tid, const float* __restrict__ oF, const int* __restrict__ src,
                       const float* __restrict__ Esrc, float* __restrict__ out,
                       float* sc, float* rb, int* ib, float* red)
{
  for (int r = 0; r < 4; ++r) {
    const int id = wg * 4 + r;
    const int b = id >> 5, p = id & 31;
    __syncthreads();
    rb[tid] = ldcv(oF + ((size_t)p * 32 + b) * 512 + tid);
    ib[tid] = src[b * 512 + tid];
    __syncthreads();
    const int w = tid >> 6, lane = tid & 63;
    for (int s = w; s < 512; s += 8) {
      const float* er = Esrc + (size_t)ib[s] * 512;
      float acc = 0.f;
#pragma unroll
      for (int i = 0; i < 8; ++i) acc = fmaf(rb[lane * 8 + i], er[lane * 8 + i], acc);
      acc = wredsum(acc);
      if (lane == 0) sc[s] = acc * SCALE_INV;
    }
    __syncthreads();
    const float mx = blockMax(sc[tid], red, tid);
    const float e = expf(sc[tid] - mx);
    const float sum = blockSum(e, red, tid);
    out[1024 + ((size_t)b * 32 + p) * 512 + tid] = e / sum;
  }
}

extern "C" __global__ void __launch_bounds__(TPB)
s2s_mega(const int* __restrict__ src, const float* __restrict__ Esrc, const float* __restrict__ Etrg,
         const float* __restrict__ Wih, const float* __restrict__ Whh,
         const float* __restrict__ bih, const float* __restrict__ bhh,
         const float* __restrict__ Wfc, const float* __restrict__ bfc,
         const float* __restrict__ Wh2o, const float* __restrict__ bh2o,
         const float* __restrict__ bout, float* __restrict__ out,
         float* __restrict__ ws, const float* __restrict__ ET, float* __restrict__ ETw)
{
  extern __shared__ float SM[];
  float* SMW = SM + L_W;
  float* LH  = SM + L_ST;
  float* sc  = SM + L_SC;
  float* rb  = SM + L_RB;
  int*   ib  = (int*)(SM + L_IB);
  float* red = SM + L_RED;
  float* hblk = SM + L_HB;
  float* gv  = SM + L_GV;
  int*   gi  = (int*)(SM + L_GI);
  int*   tokL = (int*)(SM + L_TOK);

  unsigned* sb = (unsigned*)ws;
  float* H0 = ws + OFF_H0;
  float* H1 = ws + OFF_H1;
  float* P  = ws + OFF_P;
  float* Hl = ws + OFF_HL;
  float* hD = ws + OFF_HD;
  float* oF = ws + OFF_OF;
  float* cV = ws + OFF_CV;
  int*   cI = (int*)(ws + OFF_CI);

  const int wg = blockIdx.x, tid = threadIdx.x;
  const bool useET = (ET != nullptr);
  unsigned lg = 0u;
  float c0[2] = {0.f, 0.f}, c1[2] = {0.f, 0.f};
  float accG[8];

  // layer-1 bias sums for this thread's column d = wg*2 + dl
  float bs1v[4];
  {
    const int dl = (tid >> 4) & 1;
    const int d = (wg << 1) | dl;
#pragma unroll
    for (int q = 0; q < 4; ++q)
      bs1v[q] = bih[2048 + q * 512 + d] + bhh[2048 + q * 512 + d];
  }

  // ---- setup: zero carried H state ----
  {
    const int gid = wg * TPB + tid;
    if (gid < BD) stcv(H0 + gid, 0.f);
    else if (gid < 2 * BD) stcv(H1 + gid - BD, 0.f);
  }
  // ---- P[0] = emb([SOS]) @ Wih0^T + biases (sc1 stores) ----
  {
    const int w = tid >> 6, lane = tid & 63;
    const int q = w >> 1, dl = w & 1;
    const int j = q * 512 + wg * 2 + dl;
    const float* er = Etrg + 512;               // token 1 ([SOS])
    const float* wr = Wih + (size_t)j * 512;
    float p = 0.f;
#pragma unroll
    for (int i = 0; i < 8; ++i) p = fmaf(er[lane * 8 + i], wr[lane * 8 + i], p);
    p = wredsum(p);
    p += bih[j] + bhh[j];
    if (lane < 32) stcv(P + (size_t)lane * 2048 + j, p);
  }
  if (ETw) buildETb(wg, tid, Etrg, ETw, LH);
  stageW(wg, tid, Wih, Whh, SMW);
  gbar(sb, lg);

  int cur0 = 0, cur1 = 0;
  for (int t = 0; t < 32; ++t) {
    for (int k = 0; k <= t + 1; ++k) {
      const bool doA = (k <= t), doB = (k >= 1);
      float* HlP = (t == 31 && doB) ? (Hl + (size_t)(k - 1) * BD) : nullptr;
      const int kp = (k < 32) ? k : 31;
      phaseAB(wg, tid, doA, doB,
              H0 + (size_t)cur0 * BD, H0 + (size_t)(cur0 ^ 1) * BD,
              H1 + (size_t)cur1 * BD, H1 + (size_t)(cur1 ^ 1) * BD,
              HlP, P + (size_t)kp * Bb * 2048, bs1v, SMW, LH, c0, c1);
      if (useET) {
        // fold previous step's logits (2 chunks) + argmax into k=0..2
        if (t >= 2 && k == 0) {
          phaseG(wg, tid, 0, accG, hD, ET, bout, cV, cI, hblk, gv, gi);
          if (t == 2) phaseG(wg, tid, 1, accG, hD, ET, bout, cV, cI, hblk, gv, gi);
        }
        if (t >= 3 && k == 1)
          phaseG(wg, tid, 1, accG, hD, ET, bout, cV, cI, hblk, gv, gi);
        if (t == 2 && k == 1)
          phaseHP(wg, tid, 1, true, cV, cI, Etrg, Wih, bih, bhh, P, out, tokL);
        if (t >= 3 && k == 2)
          phaseHP(wg, tid, t - 1, true, cV, cI, Etrg, Wih, bih, bhh, P, out, tokL);
      } else {
        if (t >= 2 && k == 0)
          phaseG_noET(wg, tid, hD, Etrg, bout, cV, cI, hblk, gv, gi);
        if (t >= 2 && k == 1)
          phaseHP(wg, tid, t - 1, false, cV, cI, Etrg, Wih, bih, bhh, P, out, tokL);
      }
      gbar(sb, lg);
      if (doA) cur0 ^= 1;
      if (doB) cur1 ^= 1;
    }
    if (wg < 32) phaseCDEF(wg, tid, H1 + (size_t)cur1 * BD, Wfc, bfc, src, Esrc,
                           Wh2o, bh2o, hD, sc, rb, ib, red);
    gbar(sb, lg);
    if (t == 0) {     // bootstrap: G(0), HP(0) standalone
      if (useET) {
        phaseG(wg, tid, 0, accG, hD, ET, bout, cV, cI, hblk, gv, gi);
        phaseG(wg, tid, 1, accG, hD, ET, bout, cV, cI, hblk, gv, gi);
      } else {
        phaseG_noET(wg, tid, hD, Etrg, bout, cV, cI, hblk, gv, gi);
      }
      gbar(sb, lg);
      phaseHP(wg, tid, 0, useET, cV, cI, Etrg, Wih, bih, bhh, P, out, tokL);
      gbar(sb, lg);
    }
  }
  // tail: G(31)/HP(31) folded into X / Y phases.
  phaseX(wg, tid, Hl, Wfc, bfc, oF);
  if (useET) {
    phaseG(wg, tid, 0, accG, hD, ET, bout, cV, cI, hblk, gv, gi);
    phaseG(wg, tid, 1, accG, hD, ET, bout, cV, cI, hblk, gv, gi);
  } else {
    phaseG_noET(wg, tid, hD, Etrg, bout, cV, cI, hblk, gv, gi);
  }
  gbar(sb, lg);
  phaseHP(wg, tid, 31, useET, cV, cI, Etrg, Wih, bih, bhh, P, out, tokL);
  phaseY(wg, tid, oF, src, Esrc, out, sc, rb, ib, red);
}

extern "C" void kernel_launch(void* const* d_in, const int* in_sizes, int n_in,
                              void* d_out, int out_size, void* d_ws, size_t ws_size,
                              hipStream_t stream) {
  const int*   src  = (const int*)d_in[0];
  const float* Esrc = (const float*)d_in[1];
  const float* Etrg = (const float*)d_in[2];
  const float* Wih  = (const float*)d_in[3];
  const float* Whh  = (const float*)d_in[4];
  const float* bih  = (const float*)d_in[5];
  const float* bhh  = (const float*)d_in[6];
  const float* Wfc  = (const float*)d_in[7];
  const float* bfc  = (const float*)d_in[8];
  const float* Wh2o = (const float*)d_in[9];
  const float* bh2o = (const float*)d_in[10];
  const float* bout = (const float*)d_in[11];
  float* ws = (float*)d_ws;

  const size_t needET = (OFF_ET + (size_t)512 * 32000) * sizeof(float);
  const bool useET = (ws_size >= needET);
  float* etw = useET ? (ws + OFF_ET) : nullptr;

  (void)hipMemsetAsync(d_ws, 0, 32768, stream);   // reset barrier slots + flags

  (void)hipFuncSetAttribute(reinterpret_cast<const void*>(&s2s_mega),
                            hipFuncAttributeMaxDynamicSharedMemorySize, (int)LDS_BYTES);

  s2s_mega<<<dim3(NWG), dim3(TPB), LDS_BYTES, stream>>>(
      src, Esrc, Etrg, Wih, Whh, bih, bhh, Wfc, bfc, Wh2o, bh2o, bout,
      (float*)d_out, ws, etw, etw);
}

// Round 15
// 18024.857 us; speedup vs baseline: 2.6511x; 1.0034x over previous
//
#include <hip/hip_runtime.h>
#include <math.h>

#define NWG 256
#define TPB 512
#define AGT __HIP_MEMORY_SCOPE_AGENT

// ---- sizes ----
static constexpr int Bb = 32, Dd = 512, Tt = 32, Vv = 32000;
static constexpr int BD = Bb * Dd;                       // 16384
static constexpr float SCALE_INV = 0.04419417382415922f; // 1/sqrt(512)

// ---- ws layout (float offsets). Sync region = first 32 KB. ----
// H0/H1/Hl use PAIRED layout: element (b,k) at [b>>1]*1024 + k*2 + (b&1).
static constexpr size_t OFF_H0 = 8192;
static constexpr size_t OFF_H1 = OFF_H0 + 2 * (size_t)BD;
static constexpr size_t OFF_P  = OFF_H1 + 2 * (size_t)BD;             // [32][32][2048]
static constexpr size_t OFF_HL = OFF_P + (size_t)Tt * Bb * 2048;      // [32] paired blocks
static constexpr size_t OFF_HD = OFF_HL + (size_t)Tt * BD;
static constexpr size_t OFF_OF = OFF_HD + BD;                          // [32][32][512]
static constexpr size_t OFF_CV = OFF_OF + (size_t)Tt * BD;             // [32][256]
static constexpr size_t OFF_CI = OFF_CV + 32 * 256;
static constexpr size_t OFF_ET = OFF_CI + 32 * 256;                    // ETb [16000][512][2]

// ---- LDS region offsets (floats) ----
static constexpr int L_W   = 0;       // 24 x 576 slant-packed weight rows = 13824
static constexpr int L_ST  = 13824;   // 16384: AB H-stage / ETb-build tile / CDEF+Y scratch
static constexpr int L_SC  = 13824;   //   sc  (512)  [CDEF/Y phases only]
static constexpr int L_RB  = 14336;   //   rb  (1024)
static constexpr int L_IB  = 15360;   //   ib  (512)
static constexpr int L_RED = 15872;   //   red (16)
static constexpr int L_HB  = 30208;   // 2048: G hidT block [64k][32b] swizzled
static constexpr int L_GV  = 32256;   // 256
static constexpr int L_GI  = 32512;   // 256
static constexpr int L_TOK = 32768;   // 32
static constexpr int LDS_FLOATS = 32800;
static constexpr size_t LDS_BYTES = (size_t)LDS_FLOATS * 4;   // 131200

__device__ __forceinline__ float sigm(float x) { return 1.0f / (1.0f + expf(-x)); }

// ---- IC-coherent (sc1) access: relaxed agent-scope atomics ----
__device__ __forceinline__ float ldcv(const float* p) {
  unsigned u = __hip_atomic_load((const unsigned*)p, __ATOMIC_RELAXED, AGT);
  return __builtin_bit_cast(float, u);
}
__device__ __forceinline__ void stcv(float* p, float v) {
  __hip_atomic_store((unsigned*)p, __builtin_bit_cast(unsigned, v), __ATOMIC_RELAXED, AGT);
}
__device__ __forceinline__ float2 ldcv2(const float* p) {
  unsigned long long u = __hip_atomic_load((const unsigned long long*)p, __ATOMIC_RELAXED, AGT);
  return __builtin_bit_cast(float2, u);
}
__device__ __forceinline__ void stcv2(float* p, float2 v) {
  __hip_atomic_store((unsigned long long*)p, __builtin_bit_cast(unsigned long long, v),
                     __ATOMIC_RELAXED, AGT);
}
__device__ __forceinline__ int ldcvi(const int* p) {
  return (int)__hip_atomic_load((const unsigned*)p, __ATOMIC_RELAXED, AGT);
}
__device__ __forceinline__ void stcvi(int* p, int v) {
  __hip_atomic_store((unsigned*)p, (unsigned)v, __ATOMIC_RELAXED, AGT);
}

__device__ __forceinline__ float wredsum(float v) {
#pragma unroll
  for (int off = 32; off > 0; off >>= 1) v += __shfl_xor(v, off, 64);
  return v;
}

// DPP rotate-reduce within each 16-lane row (pure VALU, no LDS pipe).
__device__ __forceinline__ float rowReduce16(float x) {
  int t;
  t = __builtin_amdgcn_update_dpp(0, __builtin_bit_cast(int, x), 0x121, 0xF, 0xF, false);
  x += __builtin_bit_cast(float, t);
  t = __builtin_amdgcn_update_dpp(0, __builtin_bit_cast(int, x), 0x122, 0xF, 0xF, false);
  x += __builtin_bit_cast(float, t);
  t = __builtin_amdgcn_update_dpp(0, __builtin_bit_cast(int, x), 0x124, 0xF, 0xF, false);
  x += __builtin_bit_cast(float, t);
  t = __builtin_amdgcn_update_dpp(0, __builtin_bit_cast(int, x), 0x128, 0xF, 0xF, false);
  x += __builtin_bit_cast(float, t);
  return x;
}

// H-stage LDS swizzle (identical on write & read; involution)
__device__ __forceinline__ int swzH(int byte) { return byte ^ (((byte >> 8) & 7) << 4); }

// ---- contention-free 2-level slot barrier ----
__device__ __forceinline__ void gbar(unsigned* sb, unsigned& lg) {
  const unsigned tgt = lg + 1u;
  asm volatile("s_waitcnt vmcnt(0)" ::: "memory");
  __syncthreads();
  const int wg = (int)blockIdx.x;
  if (threadIdx.x < 64) {
    const int lane = (int)threadIdx.x;
    if (lane == 0)
      __hip_atomic_store(&sb[wg * 16], tgt, __ATOMIC_RELAXED, AGT);
    const int g = wg >> 5;
    if ((wg & 31) == 0) {                       // group leader
      if (lane < 32) {
        const unsigned* slot = &sb[(g * 32 + lane) * 16];
        while (__hip_atomic_load(slot, __ATOMIC_RELAXED, AGT) < tgt)
          __builtin_amdgcn_s_sleep(1);
      }
      if (lane == 0)
        __hip_atomic_store(&sb[4096 + g * 16], tgt, __ATOMIC_RELAXED, AGT);
    }
    if (lane < 8) {
      const unsigned* f = &sb[4096 + lane * 16];
      while (__hip_atomic_load(f, __ATOMIC_RELAXED, AGT) < tgt)
        __builtin_amdgcn_s_sleep(1);
    }
  }
  lg = tgt;
  __syncthreads();
}

__device__ __forceinline__ float blockMax(float v, float* red, int tid) {
#pragma unroll
  for (int off = 32; off > 0; off >>= 1) v = fmaxf(v, __shfl_xor(v, off, 64));
  if ((tid & 63) == 0) red[tid >> 6] = v;
  __syncthreads();
  float m = red[0];
#pragma unroll
  for (int i = 1; i < 8; ++i) m = fmaxf(m, red[i]);
  __syncthreads();
  return m;
}

__device__ __forceinline__ float blockSum(float v, float* red, int tid) {
  v = wredsum(v);
  if ((tid & 63) == 0) red[tid >> 6] = v;
  __syncthreads();
  float s = 0.f;
#pragma unroll
  for (int i = 0; i < 8; ++i) s += red[i];
  __syncthreads();
  return s;
}

// ---- stage weights, slant-packed: row rr = m*8+q*2+dl, chunk kc at kc*36 ----
__device__ void stageW(int wg, int tid, const float* __restrict__ Wih,
                       const float* __restrict__ Whh, float* __restrict__ SMW) {
  for (int e = tid; e < 24 * 512; e += TPB) {
    const int k = e & 511, rr = e >> 9;
    const int m = rr >> 3, q = (rr >> 1) & 3, dl = rr & 1;
    const int j = q * 512 + wg * 2 + dl;
    const float* srcp = (m == 0) ? (Whh + (size_t)j * 512)
                     : (m == 1) ? (Wih + (size_t)2048 * 512 + (size_t)j * 512)
                                : (Whh + (size_t)2048 * 512 + (size_t)j * 512);
    SMW[rr * 576 + (k >> 5) * 36 + (k & 31)] = srcp[k];
  }
  __syncthreads();
}

// ---- WG-private build of ETb[v/2][k][2] from Etrg (panel [wg*128, +128)) ----
__device__ void buildETb(int wg, int tid, const float* __restrict__ Etrg,
                         float* __restrict__ ETb, float* __restrict__ SM) {
  if (wg < 250) {
    for (int tile = 0; tile < 8; ++tile) {
      const int tv = tile >> 2, tk = tile & 3;
      __syncthreads();
      for (int e = tid; e < 64 * 128; e += TPB) {
        const int vl = e >> 7, kl = e & 127;
        SM[vl * 129 + kl] = Etrg[(size_t)(wg * 128 + tv * 64 + vl) * 512 + tk * 128 + kl];
      }
      __syncthreads();
      for (int e = tid; e < 32 * 128; e += TPB) {
        const int vp = e >> 7, kl = e & 127;
        const int v = wg * 128 + tv * 64 + vp * 2;
        const int k = tk * 128 + kl;
        float2 val = make_float2(SM[(vp * 2) * 129 + kl], SM[(vp * 2 + 1) * 129 + kl]);
        stcv2(ETb + ((size_t)(v >> 1) * 512 + k) * 2, val);
      }
    }
    __syncthreads();
  }
}

// per-(m,q) dot: slant-packed W row rr x paired H fragments -> float2 (b0,b1)
__device__ __forceinline__ void dotMQ(const float* __restrict__ SMW, int rr, int kc,
                                      const float4* __restrict__ hq, float2& acc) {
  const float4* wr = (const float4*)(SMW + rr * 576 + kc * 36);
#pragma unroll
  for (int i2 = 0; i2 < 8; ++i2) {
    const float4 wv = wr[i2];
    const float4 hA = hq[i2 * 2], hB = hq[i2 * 2 + 1];
    acc.x = fmaf(wv.x, hA.x, acc.x); acc.y = fmaf(wv.x, hA.y, acc.y);
    acc.x = fmaf(wv.y, hA.z, acc.x); acc.y = fmaf(wv.y, hA.w, acc.y);
    acc.x = fmaf(wv.z, hB.x, acc.x); acc.y = fmaf(wv.z, hB.y, acc.y);
    acc.x = fmaf(wv.w, hB.z, acc.x); acc.y = fmaf(wv.w, hB.w, acc.y);
  }
}

// ---- merged LSTM phase: A = L0(pos p), B = L1(pos p-1). tid = b2*32 + dl*16 + kc.
// Load issue order rotated per-WG ((r+wg)&7) to spread IC hot-line pressure.
__device__ __forceinline__ void phaseAB(
    int wg, int tid, bool doA, bool doB,
    const float* __restrict__ H0r, float* __restrict__ H0w,
    const float* __restrict__ H1r, float* __restrict__ H1w,
    float* __restrict__ HlP, const float* __restrict__ Pp,
    const float* __restrict__ bs1v,
    const float* __restrict__ SMW, float* __restrict__ LH, float* c0, float* c1)
{
  const int b2 = tid >> 5, dl = (tid >> 4) & 1, kc = tid & 15;
  const int rot = wg & 7;
  char* LHc = (char*)LH;
  float4 s0[8], s1[8];
  __builtin_amdgcn_sched_barrier(0);
  {
    const float* p0 = H0r + tid * 4;
#pragma unroll
    for (int r = 0; r < 8; ++r) {
      const int rr = (r + rot) & 7;
      asm volatile("global_load_dwordx4 %0, %1, off sc1" : "=v"(s0[r]) : "v"(p0 + rr * 2048));
    }
  }
  if (doB) {
    const float* p1 = H1r + tid * 4;
#pragma unroll
    for (int r = 0; r < 8; ++r) {
      const int rr = (r + rot) & 7;
      asm volatile("global_load_dwordx4 %0, %1, off sc1" : "=v"(s1[r]) : "v"(p1 + rr * 2048));
    }
    asm volatile("s_waitcnt vmcnt(8)" ::: "memory");   // s0 arrived
  } else {
    asm volatile("s_waitcnt vmcnt(0)" ::: "memory");
  }
  __builtin_amdgcn_sched_barrier(0);
#pragma unroll
  for (int r = 0; r < 8; ++r) {
    const int rr = (r + rot) & 7;
    *(float4*)(LHc + swzH((rr * 512 + tid) * 16)) = s0[r];
  }
  __syncthreads();
  float4 hq[16];
#pragma unroll
  for (int i = 0; i < 16; ++i)
    hq[i] = *(const float4*)(LHc + swzH(b2 * 4096 + kc * 256 + i * 16));

  float2 acc2[12];
#pragma unroll
  for (int j = 0; j < 12; ++j) acc2[j] = make_float2(0.f, 0.f);

  if (doA) {
#pragma unroll
    for (int q = 0; q < 4; ++q) dotMQ(SMW, q * 2 + dl, kc, hq, acc2[q]);        // Whh0.H0
  }
  if (doB) {
#pragma unroll
    for (int q = 0; q < 4; ++q) dotMQ(SMW, 8 + q * 2 + dl, kc, hq, acc2[4 + q]); // Wih1.H0
    asm volatile("s_waitcnt vmcnt(0)" ::: "memory");     // s1 arrived
    __builtin_amdgcn_sched_barrier(0);
    __syncthreads();                                     // all H0 reads done
#pragma unroll
    for (int r = 0; r < 8; ++r) {
      const int rr = (r + rot) & 7;
      *(float4*)(LHc + swzH((rr * 512 + tid) * 16)) = s1[r];
    }
    __syncthreads();
#pragma unroll
    for (int i = 0; i < 16; ++i)
      hq[i] = *(const float4*)(LHc + swzH(b2 * 4096 + kc * 256 + i * 16));
#pragma unroll
    for (int q = 0; q < 4; ++q) dotMQ(SMW, 16 + q * 2 + dl, kc, hq, acc2[8 + q]); // Whh1.H1
  }

#pragma unroll
  for (int j = 0; j < 12; ++j) {
    if (j < 4 ? !doA : !doB) continue;
    acc2[j].x = rowReduce16(acc2[j].x);
    acc2[j].y = rowReduce16(acc2[j].y);
  }

  if (kc == 0) {                       // 32 lanes/WG own (b2, dl); d = wg*2+dl
    const int d = (wg << 1) | dl;
    if (doA) {
#pragma unroll
      for (int p = 0; p < 2; ++p) {
        const int b = b2 * 2 + p;
        const float* pb = Pp + b * 2048 + d;
        const float gi = (p ? acc2[0].y : acc2[0].x) + pb[0];
        const float gf = (p ? acc2[1].y : acc2[1].x) + pb[512];
        const float gg = (p ? acc2[2].y : acc2[2].x) + pb[1024];
        const float go = (p ? acc2[3].y : acc2[3].x) + pb[1536];
        c0[p] = sigm(gf) * c0[p] + sigm(gi) * tanhf(gg);
        stcv(H0w + b2 * 1024 + d * 2 + p, sigm(go) * tanhf(c0[p]));
      }
    }
    if (doB) {
#pragma unroll
      for (int p = 0; p < 2; ++p) {
        const float gi = (p ? acc2[4].y : acc2[4].x) + (p ? acc2[8].y  : acc2[8].x)  + bs1v[0];
        const float gf = (p ? acc2[5].y : acc2[5].x) + (p ? acc2[9].y  : acc2[9].x)  + bs1v[1];
        const float gg = (p ? acc2[6].y : acc2[6].x) + (p ? acc2[10].y : acc2[10].x) + bs1v[2];
        const float go = (p ? acc2[7].y : acc2[7].x) + (p ? acc2[11].y : acc2[11].x) + bs1v[3];
        c1[p] = sigm(gf) * c1[p] + sigm(gi) * tanhf(gg);
        const float hn = sigm(go) * tanhf(c1[p]);
        stcv(H1w + b2 * 1024 + d * 2 + p, hn);
        if (HlP) stcv(HlP + b2 * 1024 + d * 2 + p, hn);
      }
    }
  }
}

// ---- fused fc + attention + context + h2o for one batch row (WGs 0..31) ----
__device__ void phaseCDEF(int b, int tid, const float* __restrict__ H1c,
                          const float* __restrict__ Wfc, const float* __restrict__ bfc,
                          const int* __restrict__ src, const float* __restrict__ Esrc,
                          const float* __restrict__ Wh2o, const float* __restrict__ bh2o,
                          float* __restrict__ hD, float* sc, float* rb, int* ib, float* red)
{
  rb[tid] = ldcv(H1c + (b >> 1) * 1024 + tid * 2 + (b & 1));  // paired layout
  ib[tid] = src[b * 512 + tid];
  __syncthreads();
  const int w = tid >> 6, lane = tid & 63;
  for (int d = w; d < 512; d += 8) {            // fc_out
    const float* wr = Wfc + (size_t)d * 512;
    float p = 0.f;
#pragma unroll
    for (int i = 0; i < 8; ++i) p = fmaf(rb[lane * 8 + i], wr[lane * 8 + i], p);
    p = wredsum(p);
    if (lane == 0) rb[512 + d] = p + bfc[d];
  }
  __syncthreads();
  for (int s = w; s < 512; s += 8) {            // scores
    const float* er = Esrc + (size_t)ib[s] * 512;
    float p = 0.f;
#pragma unroll
    for (int i = 0; i < 8; ++i) p = fmaf(rb[512 + lane * 8 + i], er[lane * 8 + i], p);
    p = wredsum(p);
    if (lane == 0) sc[s] = p * SCALE_INV;
  }
  __syncthreads();
  const float mx = blockMax(sc[tid], red, tid);
  const float e = expf(sc[tid] - mx);
  sc[tid] = e;
  const float sum = blockSum(e, red, tid);
  const float inv = 1.0f / sum;
  float acc = 0.f;
#pragma unroll 4
  for (int s = 0; s < 512; ++s) acc = fmaf(sc[s], Esrc[(size_t)ib[s] * 512 + tid], acc);
  rb[tid] = acc * inv;                          // ctx into rb[0:512]
  __syncthreads();
  for (int d = w; d < 512; d += 8) {            // h2o + relu
    const float* wr = Wh2o + (size_t)d * 1024;
    float p = 0.f;
#pragma unroll
    for (int i = 0; i < 8; ++i) p = fmaf(rb[512 + lane * 8 + i], wr[lane * 8 + i], p);
#pragma unroll
    for (int i = 0; i < 8; ++i) p = fmaf(rb[lane * 8 + i], wr[512 + lane * 8 + i], p);
    p = wredsum(p);
    if (lane == 0) stcv(hD + (size_t)b * 512 + d, fmaxf(p + bh2o[d], 0.f));
  }
  __syncthreads();
}

// ---- single-pass logits chunk: k in [chunk*256, chunk*256+256), all 32 b ----
__device__ void phaseG(int wg, int tid, int chunk, float* __restrict__ accG,
                       const float* __restrict__ hD, const float* __restrict__ ETb,
                       const float* __restrict__ bout, float* __restrict__ candV,
                       int* __restrict__ candI, float* __restrict__ hblk,
                       float* __restrict__ gv, int* __restrict__ gi)
{
  if (wg >= 250) return;
  if (chunk == 0) {
#pragma unroll
    for (int j = 0; j < 8; ++j) accG[j] = 0.f;
  }
  const int vp = tid >> 3, bh = tid & 7;
  const int v = wg * 128 + vp * 2;
  const float* ep = ETb + (size_t)(v >> 1) * 1024 + chunk * 512;
  const int fk = tid & 63, fb0 = tid >> 6;
  char* hb = (char*)hblk;

  for (int blk = 0; blk < 4; ++blk) {
    const int kb = chunk * 256 + blk * 64;
    __syncthreads();
#pragma unroll
    for (int i = 0; i < 4; ++i) {               // fill hblk (coalesced hD read)
      const int b = fb0 + i * 8;
      const float hv = ldcv(hD + (size_t)b * 512 + kb + fk);
      const int byte = fk * 128 + (((b >> 2) * 16) ^ ((fk & 7) << 4)) + ((b & 3) << 2);
      *(float*)(hb + byte) = hv;
    }
    __syncthreads();
#pragma unroll 8
    for (int kk = 0; kk < 64; kk += 2) {
      const float4 e4 = *(const float4*)ep; ep += 4;   // (k,v0)(k,v1)(k+1,v0)(k+1,v1)
      const float4 ha = *(const float4*)(hb + kk * 128 + ((bh * 16) ^ ((kk & 7) << 4)));
      const float4 hbv = *(const float4*)(hb + (kk + 1) * 128 + ((bh * 16) ^ (((kk + 1) & 7) << 4)));
      accG[0] = fmaf(e4.x, ha.x, accG[0]);  accG[4] = fmaf(e4.y, ha.x, accG[4]);
      accG[1] = fmaf(e4.x, ha.y, accG[1]);  accG[5] = fmaf(e4.y, ha.y, accG[5]);
      accG[2] = fmaf(e4.x, ha.z, accG[2]);  accG[6] = fmaf(e4.y, ha.z, accG[6]);
      accG[3] = fmaf(e4.x, ha.w, accG[3]);  accG[7] = fmaf(e4.y, ha.w, accG[7]);
      accG[0] = fmaf(e4.z, hbv.x, accG[0]); accG[4] = fmaf(e4.w, hbv.x, accG[4]);
      accG[1] = fmaf(e4.z, hbv.y, accG[1]); accG[5] = fmaf(e4.w, hbv.y, accG[5]);
      accG[2] = fmaf(e4.z, hbv.z, accG[2]); accG[6] = fmaf(e4.w, hbv.z, accG[6]);
      accG[3] = fmaf(e4.z, hbv.w, accG[3]); accG[7] = fmaf(e4.w, hbv.w, accG[7]);
    }
  }

  if (chunk == 1) {                             // bout + argmax + write candidates
    const float bo0 = bout[v], bo1 = bout[v + 1];
    const int w = tid >> 6;
#pragma unroll
    for (int j = 0; j < 4; ++j) {
      const float va = accG[j] + bo0, vb = accG[4 + j] + bo1;
      float bv; int bi;
      if (vb > va) { bv = vb; bi = v + 1; } else { bv = va; bi = v; }
#pragma unroll
      for (int off = 8; off < 64; off <<= 1) {
        const float ov = __shfl_xor(bv, off, 64); const int oi = __shfl_xor(bi, off, 64);
        if (ov > bv || (ov == bv && oi < bi)) { bv = ov; bi = oi; }
      }
      if ((tid & 63) < 8) {
        gv[(bh * 4 + j) * 8 + w] = bv;
        gi[(bh * 4 + j) * 8 + w] = bi;
      }
    }
    __syncthreads();
    if (tid < 32) {
      float bv = -INFINITY; int bi = 0;
      for (int w2 = 0; w2 < 8; ++w2) {
        const float vv = gv[tid * 8 + w2]; const int ii = gi[tid * 8 + w2];
        if (vv > bv || (vv == bv && ii < bi)) { bv = vv; bi = ii; }
      }
      stcv(candV + (size_t)tid * 256 + wg, bv);
      stcvi(candI + tid * 256 + wg, bi);
    }
    __syncthreads();
  }
}

// ---- fallback logits (row-major E), wave-per-v ----
__device__ void phaseG_noET(int wg, int tid, const float* __restrict__ hD,
                            const float* __restrict__ Etrg, const float* __restrict__ bout,
                            float* __restrict__ candV, int* __restrict__ candI,
                            float* rb, float* gv, int* gi)
{
  const int b = wg >> 3, vb = wg & 7;
  rb[tid] = ldcv(hD + (size_t)b * 512 + tid);
  __syncthreads();
  const int w = tid >> 6, lane = tid & 63;
  float bv = -INFINITY; int bi = 0;
  for (int v = vb * 4000 + w; v < (vb + 1) * 4000; v += 8) {
    const float* er = Etrg + (size_t)v * 512;
    float p = 0.f;
#pragma unroll
    for (int i = 0; i < 8; ++i) p = fmaf(rb[lane * 8 + i], er[lane * 8 + i], p);
    p = wredsum(p);
    p += bout[v];
    if (p > bv || (p == bv && v < bi)) { bv = p; bi = v; }
  }
  if (lane == 0) { gv[w] = bv; gi[w] = bi; }
  __syncthreads();
  if (tid == 0) {
    float fv = -INFINITY; int fi = 0;
    for (int w2 = 0; w2 < 8; ++w2)
      if (gv[w2] > fv || (gv[w2] == fv && gi[w2] < fi)) { fv = gv[w2]; fi = gi[w2]; }
    stcv(candV + (size_t)b * 256 + vb, fv);
    stcvi(candI + b * 256 + vb, fi);
  }
  __syncthreads();
}

// ---- token argmax finalize + P[t+1] projection ----
__device__ void phaseHP(int wg, int tid, int t, bool useET,
                        const float* __restrict__ candV, const int* __restrict__ candI,
                        const float* __restrict__ Etrg, const float* __restrict__ Wih,
                        const float* __restrict__ bih, const float* __restrict__ bhh,
                        float* __restrict__ P, float* __restrict__ out, int* tokL)
{
  const int nslot = useET ? 250 : 8;
  {
    const int b = tid >> 4, sl = tid & 15;
    float bv = -INFINITY; int bi = 0x7fffffff;
    for (int s = sl; s < nslot; s += 16) {
      const float vv = ldcv(candV + (size_t)b * 256 + s);
      const int ii = ldcvi(candI + b * 256 + s);
      if (vv > bv || (vv == bv && ii < bi)) { bv = vv; bi = ii; }
    }
#pragma unroll
    for (int off = 1; off < 16; off <<= 1) {
      const float ov = __shfl_xor(bv, off, 64); const int oi = __shfl_xor(bi, off, 64);
      if (ov > bv || (ov == bv && oi < bi)) { bv = ov; bi = oi; }
    }
    if (sl == 0) {
      tokL[b] = bi;
      if (wg == 0) stcv(out + b * 32 + t, (float)bi);   // tokens[:,1:][b][t]
    }
  }
  __syncthreads();
  if (t < 31) {
    const int w = tid >> 6, lane = tid & 63;
    const int q = w >> 1, dl = w & 1;
    const int j = q * 512 + wg * 2 + dl;
    const float* wr = Wih + (size_t)j * 512;
    const float bsum = bih[j] + bhh[j];
    for (int b = 0; b < 32; ++b) {
      const float* er = Etrg + (size_t)tokL[b] * 512;
      float p = 0.f;
#pragma unroll
      for (int i = 0; i < 8; ++i) p = fmaf(er[lane * 8 + i], wr[lane * 8 + i], p);
      p = wredsum(p);
      if (lane == 0) stcv(P + ((size_t)(t + 1) * 32 + b) * 2048 + j, p + bsum);
    }
  }
  __syncthreads();
}

// ---- outfc[p][b][:] = Hlast[p][b] @ Wfc^T + bfc (paired Hl layout) ----
__device__ void phaseX(int wg, int tid, const float* __restrict__ Hl, const float* __restrict__ Wfc,
                       const float* __restrict__ bfc, float* __restrict__ oF)
{
  const int p = wg >> 3, bq = wg & 7;
  const int w = tid >> 6, lane = tid & 63;
  for (int u = w; u < 1024; u += 8) {
    const int b2 = bq * 2 + (u >> 9), d = u & 511;
    const float* hr = Hl + (size_t)p * BD + b2 * 1024;
    const float* wr = Wfc + (size_t)d * 512;
    float ax = 0.f, ay = 0.f;
#pragma unroll
    for (int i = 0; i < 8; ++i) {
      const float2 hv = ldcv2(hr + (lane * 8 + i) * 2);
      const float wv = wr[lane * 8 + i];
      ax = fmaf(hv.x, wv, ax);
      ay = fmaf(hv.y, wv, ay);
    }
    ax = wredsum(ax); ay = wredsum(ay);
    if (lane == 0) {
      stcv(oF + ((size_t)p * 32 + b2 * 2    ) * 512 + d, ax + bfc[d]);
      stcv(oF + ((size_t)p * 32 + b2 * 2 + 1) * 512 + d, ay + bfc[d]);
    }
  }
}

// ---- final attn rows ----
__device__ void phaseY(int wg, int tid, const float* __restrict__ oF, const int* __restrict__ src,
                       const float* __restrict__ Esrc, float* __restrict__ out,
                       float* sc, float* rb, int* ib, float* red)
{
  for (int r = 0; r < 4; ++r) {
    const int id = wg * 4 + r;
    const int b = id >> 5, p = id & 31;
    __syncthreads();
    rb[tid] = ldcv(oF + ((size_t)p * 32 + b) * 512 + tid);
    ib[tid] = src[b * 512 + tid];
    __syncthreads();
    const int w = tid >> 6, lane = tid & 63;
    for (int s = w; s < 512; s += 8) {
      const float* er = Esrc + (size_t)ib[s] * 512;
      float acc = 0.f;
#pragma unroll
      for (int i = 0; i < 8; ++i) acc = fmaf(rb[lane * 8 + i], er[lane * 8 + i], acc);
      acc = wredsum(acc);
      if (lane == 0) sc[s] = acc * SCALE_INV;
    }
    __syncthreads();
    const float mx = blockMax(sc[tid], red, tid);
    const float e = expf(sc[tid] - mx);
    const float sum = blockSum(e, red, tid);
    out[1024 + ((size_t)b * 32 + p) * 512 + tid] = e / sum;
  }
}

extern "C" __global__ void __launch_bounds__(TPB)
s2s_mega(const int* __restrict__ src, const float* __restrict__ Esrc, const float* __restrict__ Etrg,
         const float* __restrict__ Wih, const float* __restrict__ Whh,
         const float* __restrict__ bih, const float* __restrict__ bhh,
         const float* __restrict__ Wfc, const float* __restrict__ bfc,
         const float* __restrict__ Wh2o, const float* __restrict__ bh2o,
         const float* __restrict__ bout, float* __restrict__ out,
         float* __restrict__ ws, const float* __restrict__ ET, float* __restrict__ ETw)
{
  extern __shared__ float SM[];
  float* SMW = SM + L_W;
  float* LH  = SM + L_ST;
  float* sc  = SM + L_SC;
  float* rb  = SM + L_RB;
  int*   ib  = (int*)(SM + L_IB);
  float* red = SM + L_RED;
  float* hblk = SM + L_HB;
  float* gv  = SM + L_GV;
  int*   gi  = (int*)(SM + L_GI);
  int*   tokL = (int*)(SM + L_TOK);

  unsigned* sb = (unsigned*)ws;
  float* H0 = ws + OFF_H0;
  float* H1 = ws + OFF_H1;
  float* P  = ws + OFF_P;
  float* Hl = ws + OFF_HL;
  float* hD = ws + OFF_HD;
  float* oF = ws + OFF_OF;
  float* cV = ws + OFF_CV;
  int*   cI = (int*)(ws + OFF_CI);

  const int wg = blockIdx.x, tid = threadIdx.x;
  const bool useET = (ET != nullptr);
  unsigned lg = 0u;
  float c0[2] = {0.f, 0.f}, c1[2] = {0.f, 0.f};
  float accG[8];

  // layer-1 bias sums for this thread's column d = wg*2 + dl
  float bs1v[4];
  {
    const int dl = (tid >> 4) & 1;
    const int d = (wg << 1) | dl;
#pragma unroll
    for (int q = 0; q < 4; ++q)
      bs1v[q] = bih[2048 + q * 512 + d] + bhh[2048 + q * 512 + d];
  }

  // ---- setup: zero carried H state ----
  {
    const int gid = wg * TPB + tid;
    if (gid < BD) stcv(H0 + gid, 0.f);
    else if (gid < 2 * BD) stcv(H1 + gid - BD, 0.f);
  }
  // ---- P[0] = emb([SOS]) @ Wih0^T + biases (sc1 stores) ----
  {
    const int w = tid >> 6, lane = tid & 63;
    const int q = w >> 1, dl = w & 1;
    const int j = q * 512 + wg * 2 + dl;
    const float* er = Etrg + 512;               // token 1 ([SOS])
    const float* wr = Wih + (size_t)j * 512;
    float p = 0.f;
#pragma unroll
    for (int i = 0; i < 8; ++i) p = fmaf(er[lane * 8 + i], wr[lane * 8 + i], p);
    p = wredsum(p);
    p += bih[j] + bhh[j];
    if (lane < 32) stcv(P + (size_t)lane * 2048 + j, p);
  }
  if (ETw) buildETb(wg, tid, Etrg, ETw, LH);
  stageW(wg, tid, Wih, Whh, SMW);
  gbar(sb, lg);

  int cur0 = 0, cur1 = 0;
  for (int t = 0; t < 32; ++t) {
    for (int k = 0; k <= t + 1; ++k) {
      const bool doA = (k <= t), doB = (k >= 1);
      float* HlP = (t == 31 && doB) ? (Hl + (size_t)(k - 1) * BD) : nullptr;
      const int kp = (k < 32) ? k : 31;
      phaseAB(wg, tid, doA, doB,
              H0 + (size_t)cur0 * BD, H0 + (size_t)(cur0 ^ 1) * BD,
              H1 + (size_t)cur1 * BD, H1 + (size_t)(cur1 ^ 1) * BD,
              HlP, P + (size_t)kp * Bb * 2048, bs1v, SMW, LH, c0, c1);
      if (useET) {
        if (t >= 4) {
          // folded schedule: CDEF(t-1)@k0, G(t-1) chunks @k1,k2, HP(t-1)@k3.
          // P[t] first read at k=t >= 4 > 3: safe.
          if (k == 0 && wg < 32)
            phaseCDEF(wg, tid, H1 + (size_t)cur1 * BD, Wfc, bfc, src, Esrc,
                      Wh2o, bh2o, hD, sc, rb, ib, red);
          if (k == 1) phaseG(wg, tid, 0, accG, hD, ET, bout, cV, cI, hblk, gv, gi);
          if (k == 2) phaseG(wg, tid, 1, accG, hD, ET, bout, cV, cI, hblk, gv, gi);
          if (k == 3) phaseHP(wg, tid, t - 1, true, cV, cI, Etrg, Wih, bih, bhh, P, out, tokL);
        } else if (t == 3) {
          if (k == 0) phaseG(wg, tid, 0, accG, hD, ET, bout, cV, cI, hblk, gv, gi);
          if (k == 1) phaseG(wg, tid, 1, accG, hD, ET, bout, cV, cI, hblk, gv, gi);
          if (k == 2) phaseHP(wg, tid, 2, true, cV, cI, Etrg, Wih, bih, bhh, P, out, tokL);
        } else if (t == 2) {
          if (k == 0) {
            phaseG(wg, tid, 0, accG, hD, ET, bout, cV, cI, hblk, gv, gi);
            phaseG(wg, tid, 1, accG, hD, ET, bout, cV, cI, hblk, gv, gi);
          }
          if (k == 1) phaseHP(wg, tid, 1, true, cV, cI, Etrg, Wih, bih, bhh, P, out, tokL);
        }
      } else {
        if (t >= 2 && k == 0)
          phaseG_noET(wg, tid, hD, Etrg, bout, cV, cI, hblk, gv, gi);
        if (t >= 2 && k == 1)
          phaseHP(wg, tid, t - 1, false, cV, cI, Etrg, Wih, bih, bhh, P, out, tokL);
      }
      gbar(sb, lg);
      if (doA) cur0 ^= 1;
      if (doB) cur1 ^= 1;
    }
    // standalone CDEF phase only where the fold can't apply
    if (!useET || t <= 2 || t == 31) {
      if (wg < 32) phaseCDEF(wg, tid, H1 + (size_t)cur1 * BD, Wfc, bfc, src, Esrc,
                             Wh2o, bh2o, hD, sc, rb, ib, red);
      gbar(sb, lg);
    }
    if (t == 0) {     // bootstrap: G(0), HP(0) standalone
      if (useET) {
        phaseG(wg, tid, 0, accG, hD, ET, bout, cV, cI, hblk, gv, gi);
        phaseG(wg, tid, 1, accG, hD, ET, bout, cV, cI, hblk, gv, gi);
      } else {
        phaseG_noET(wg, tid, hD, Etrg, bout, cV, cI, hblk, gv, gi);
      }
      gbar(sb, lg);
      phaseHP(wg, tid, 0, useET, cV, cI, Etrg, Wih, bih, bhh, P, out, tokL);
      gbar(sb, lg);
    }
  }
  // tail: G(31)/HP(31) folded into X / Y phases.
  phaseX(wg, tid, Hl, Wfc, bfc, oF);
  if (useET) {
    phaseG(wg, tid, 0, accG, hD, ET, bout, cV, cI, hblk, gv, gi);
    phaseG(wg, tid, 1, accG, hD, ET, bout, cV, cI, hblk, gv, gi);
  } else {
    phaseG_noET(wg, tid, hD, Etrg, bout, cV, cI, hblk, gv, gi);
  }
  gbar(sb, lg);
  phaseHP(wg, tid, 31, useET, cV, cI, Etrg, Wih, bih, bhh, P, out, tokL);
  phaseY(wg, tid, oF, src, Esrc, out, sc, rb, ib, red);
}

extern "C" void kernel_launch(void* const* d_in, const int* in_sizes, int n_in,
                              void* d_out, int out_size, void* d_ws, size_t ws_size,
                              hipStream_t stream) {
  const int*   src  = (const int*)d_in[0];
  const float* Esrc = (const float*)d_in[1];
  const float* Etrg = (const float*)d_in[2];
  const float* Wih  = (const float*)d_in[3];
  const float* Whh  = (const float*)d_in[4];
  const float* bih  = (const float*)d_in[5];
  const float* bhh  = (const float*)d_in[6];
  const float* Wfc  = (const float*)d_in[7];
  const float* bfc  = (const float*)d_in[8];
  const float* Wh2o = (const float*)d_in[9];
  const float* bh2o = (const float*)d_in[10];
  const float* bout = (const float*)d_in[11];
  float* ws = (float*)d_ws;

  const size_t needET = (OFF_ET + (size_t)512 * 32000) * sizeof(float);
  const bool useET = (ws_size >= needET);
  float* etw = useET ? (ws + OFF_ET) : nullptr;

  (void)hipMemsetAsync(d_ws, 0, 32768, stream);   // reset barrier slots + flags

  (void)hipFuncSetAttribute(reinterpret_cast<const void*>(&s2s_mega),
                            hipFuncAttributeMaxDynamicSharedMemorySize, (int)LDS_BYTES);

  s2s_mega<<<dim3(NWG), dim3(TPB), LDS_BYTES, stream>>>(
      src, Esrc, Etrg, Wih, Whh, bih, bhh, Wfc, bfc, Wh2o, bh2o, bout,
      (float*)d_out, ws, etw, etw);
}